// Round 4
// baseline (962.553 us; speedup 1.0000x reference)
//
#include <hip/hip_runtime.h>
#include <math.h>

#define HEADS 4
#define EPS_BN 1e-5f

__device__ __forceinline__ float lrelu(float x) { return x > 0.f ? x : 0.2f * x; }

// ---------------- edge dtype probe + convert ----------------
__global__ void k_detect64(const int* __restrict__ ei, int* flag, int nwords) {
    if (blockIdx.x == 0 && threadIdx.x == 0) {
        int zeros = 0;
        int lim = nwords < 256 ? nwords : 256;
        for (int i = 1; i < lim; i += 2) zeros += (ei[i] == 0);
        *flag = (zeros > lim / 4) ? 1 : 0;
    }
}

__global__ void k_convert(const int* __restrict__ ei, const int* __restrict__ flag,
                          int* __restrict__ out, int n) {
    int i = blockIdx.x * blockDim.x + threadIdx.x;
    int f = *flag;  // uniform
    if (i < n) out[i] = f ? ei[2 * i] : ei[i];
}

// ---------------- CSR build ----------------
__global__ void k_deg_init(int* deg, int N) {
    int i = blockIdx.x * blockDim.x + threadIdx.x;
    if (i < N) deg[i] = 1;  // self loop
}

__global__ void k_deg_count(const int* __restrict__ dst, int* deg, int E) {
    int i = blockIdx.x * blockDim.x + threadIdx.x;
    if (i < E) atomicAdd(&deg[dst[i]], 1);
}

__global__ void k_scan1(const int* __restrict__ deg, int* rowptr, int* bsum, int N) {
    __shared__ int lds[256];
    int t = threadIdx.x, n = blockIdx.x * 256 + t;
    int v = (n < N) ? deg[n] : 0;
    int xv = v;
    lds[t] = xv;
    __syncthreads();
    for (int off = 1; off < 256; off <<= 1) {
        int tmp = (t >= off) ? lds[t - off] : 0;
        __syncthreads();
        xv += tmp;
        lds[t] = xv;
        __syncthreads();
    }
    if (n < N) rowptr[n + 1] = xv;
    if (t == 255) bsum[blockIdx.x] = xv;
}

__global__ void k_scan2(int* bsum, int nb) {
    __shared__ int lds[256];
    int t = threadIdx.x;
    int v = (t < nb) ? bsum[t] : 0;
    int xv = v;
    lds[t] = xv;
    __syncthreads();
    for (int off = 1; off < 256; off <<= 1) {
        int tmp = (t >= off) ? lds[t - off] : 0;
        __syncthreads();
        xv += tmp;
        lds[t] = xv;
        __syncthreads();
    }
    if (t < nb) bsum[t] = xv - v;  // exclusive
}

__global__ void k_scan3(int* rowptr, const int* __restrict__ bsum, int N) {
    int n = blockIdx.x * 256 + threadIdx.x;
    if (n < N) rowptr[n + 1] += bsum[blockIdx.x];
    if (n == 0) rowptr[0] = 0;
}

__global__ void k_cursor(const int* __restrict__ rowptr, int* cursor, int N) {
    int n = blockIdx.x * blockDim.x + threadIdx.x;
    if (n < N) cursor[n] = rowptr[n];
}

__global__ void k_scatter(const int* __restrict__ src, const int* __restrict__ dst,
                          int* cursor, int* eidx, int E, int N) {
    int i = blockIdx.x * blockDim.x + threadIdx.x;
    if (i < E) {
        int s = src[i], d = dst[i];
        int pos = atomicAdd(&cursor[d], 1);
        eidx[pos] = s;
    } else if (i < E + N) {
        int n_ = i - E;
        int pos = atomicAdd(&cursor[n_], 1);
        eidx[pos] = n_;  // self loop
    }
}

// ---------------- GEMM: out[N,M] = A[N,K] @ W[K,M] ----------------
template <int M, int K>
__global__ __launch_bounds__(256) void k_gemm(const float* __restrict__ A,
                                              const float* __restrict__ W,
                                              float* __restrict__ out, int N) {
    __shared__ float Ast[32 * 68];  // [k][row]
    __shared__ float Wst[32 * 68];  // [k][col]
    const int tid = threadIdx.x;
    const int rowbase = blockIdx.x * 64, colbase = blockIdx.y * 64;
    const int tx = tid & 15, ty = tid >> 4;
    const int ar = tid >> 2, ag = tid & 3;
    const int wk = tid >> 4, wc = (tid & 15) * 4;
    float acc[4][4] = {{0.f, 0.f, 0.f, 0.f}, {0.f, 0.f, 0.f, 0.f},
                       {0.f, 0.f, 0.f, 0.f}, {0.f, 0.f, 0.f, 0.f}};
    const int arow = min(rowbase + ar, N - 1);

    for (int k0 = 0; k0 < K; k0 += 32) {
        const float* Ap = A + (size_t)arow * K + k0 + ag * 4;
        float4 a0 = *(const float4*)Ap;
        float4 a1 = *(const float4*)(Ap + 16);
        float4 wv0 = *(const float4*)(W + (size_t)(k0 + wk) * M + colbase + wc);
        float4 wv1 = *(const float4*)(W + (size_t)(k0 + wk + 16) * M + colbase + wc);
#pragma unroll
        for (int j = 0; j < 4; j++) {
            Ast[(ag * 4 + j) * 68 + ar] = ((const float*)&a0)[j];
            Ast[((ag + 4) * 4 + j) * 68 + ar] = ((const float*)&a1)[j];
        }
        *(float4*)&Wst[wk * 68 + wc] = wv0;
        *(float4*)&Wst[(wk + 16) * 68 + wc] = wv1;
        __syncthreads();
#pragma unroll
        for (int k = 0; k < 32; k++) {
            float4 av = *(const float4*)&Ast[k * 68 + ty * 4];
            float4 wv2 = *(const float4*)&Wst[k * 68 + tx * 4];
#pragma unroll
            for (int i = 0; i < 4; i++)
#pragma unroll
                for (int j = 0; j < 4; j++)
                    acc[i][j] += ((const float*)&av)[i] * ((const float*)&wv2)[j];
        }
        __syncthreads();
    }
#pragma unroll
    for (int i = 0; i < 4; i++) {
        int r = rowbase + ty * 4 + i;
        if (r < N)
            *(float4*)&out[(size_t)r * M + colbase + tx * 4] =
                make_float4(acc[i][0], acc[i][1], acc[i][2], acc[i][3]);
    }
}

// ---------------- attention scores, layers 0/1 ----------------
__global__ void k_att32(const float* __restrict__ xp, const float* __restrict__ att_s,
                        const float* __restrict__ att_d, float* __restrict__ a_s,
                        float* __restrict__ a_d, int N) {
    int wid = (blockIdx.x * blockDim.x + threadIdx.x) >> 6;
    int lane = threadIdx.x & 63;
    if (wid >= N) return;
    const float* xr = xp + (size_t)wid * 128;
    float x0 = xr[lane], x1 = xr[lane + 64];
    float ps0 = x0 * att_s[lane], ps1 = x1 * att_s[lane + 64];
    float pd0 = x0 * att_d[lane], pd1 = x1 * att_d[lane + 64];
    for (int m = 16; m >= 1; m >>= 1) {
        ps0 += __shfl_xor(ps0, m, 64);
        ps1 += __shfl_xor(ps1, m, 64);
        pd0 += __shfl_xor(pd0, m, 64);
        pd1 += __shfl_xor(pd1, m, 64);
    }
    if ((lane & 31) == 0) {
        int h = lane >> 5;
        a_s[wid * 4 + h] = ps0;
        a_s[wid * 4 + 2 + h] = ps1;
        a_d[wid * 4 + h] = pd0;
        a_d[wid * 4 + 2 + h] = pd1;
    }
}

// ---------------- layer 2 score precompute ----------------
__global__ void k_makeWt(const float* __restrict__ W2, const float* __restrict__ as2,
                         const float* __restrict__ ad2, float* __restrict__ Wt) {
    int wid = (blockIdx.x * blockDim.x + threadIdx.x) >> 6;
    int lane = threadIdx.x & 63;
    if (wid >= 1024) return;
    int k = wid & 127, hh = (wid >> 7) & 3, isd = wid >> 9;
    const float* att = isd ? ad2 : as2;
    float v = W2[(size_t)k * 512 + hh * 128 + lane] * att[hh * 128 + lane] +
              W2[(size_t)k * 512 + hh * 128 + 64 + lane] * att[hh * 128 + 64 + lane];
    for (int m = 32; m >= 1; m >>= 1) v += __shfl_xor(v, m, 64);
    if (lane == 0) Wt[isd * 512 + hh * 128 + k] = v;
}

// ---------------- layer 2 scores from h ----------------
__global__ void k_attW(const float* __restrict__ hb, const float* __restrict__ Wt,
                       float* __restrict__ a_s, float* __restrict__ a_d, int N) {
    int wid = (blockIdx.x * blockDim.x + threadIdx.x) >> 6;
    int lane = threadIdx.x & 63;
    if (wid >= N) return;
    float x0 = hb[(size_t)wid * 128 + lane], x1 = hb[(size_t)wid * 128 + 64 + lane];
    float ts[4], td[4];
#pragma unroll
    for (int hh = 0; hh < 4; hh++) {
        ts[hh] = x0 * Wt[hh * 128 + lane] + x1 * Wt[hh * 128 + 64 + lane];
        td[hh] = x0 * Wt[512 + hh * 128 + lane] + x1 * Wt[512 + hh * 128 + 64 + lane];
    }
    for (int m = 32; m >= 1; m >>= 1) {
#pragma unroll
        for (int hh = 0; hh < 4; hh++) {
            ts[hh] += __shfl_xor(ts[hh], m, 64);
            td[hh] += __shfl_xor(td[hh], m, 64);
        }
    }
    if (lane == 0) {
#pragma unroll
        for (int hh = 0; hh < 4; hh++) {
            a_s[wid * 4 + hh] = ts[hh];
            a_d[wid * 4 + hh] = td[hh];
        }
    }
}

// ---------------- edge softmax weights: one wave per dst node, lanes over edges ----------------
// Writes unnormalized p per edge (wp[j], float4 over heads) and 1/den per node.
// Exact softmax (true max then exp) — no online rescale.
__global__ void k_edgew(const float* __restrict__ a_s, const float* __restrict__ a_d,
                        const int* __restrict__ rowptr, const int* __restrict__ eidx,
                        float4* __restrict__ wp, float4* __restrict__ invden, int N) {
    int d = (blockIdx.x * blockDim.x + threadIdx.x) >> 6;
    int lane = threadIdx.x & 63;
    if (d >= N) return;
    float4 ad4 = *(const float4*)(a_d + (size_t)d * 4);
    int jb = rowptr[d], je = rowptr[d + 1], deg = je - jb;
    int j = jb + lane;
    if (deg <= 64) {
        float e[4] = {-INFINITY, -INFINITY, -INFINITY, -INFINITY};
        if (j < je) {
            int s = eidx[j];
            float4 as4 = *(const float4*)(a_s + (size_t)s * 4);
#pragma unroll
            for (int hh = 0; hh < 4; hh++)
                e[hh] = lrelu(((const float*)&as4)[hh] + ((const float*)&ad4)[hh]);
        }
        float m[4] = {e[0], e[1], e[2], e[3]};
        for (int off = 32; off >= 1; off >>= 1) {
#pragma unroll
            for (int hh = 0; hh < 4; hh++) m[hh] = fmaxf(m[hh], __shfl_xor(m[hh], off, 64));
        }
        float p[4], den[4];
#pragma unroll
        for (int hh = 0; hh < 4; hh++) {
            p[hh] = (j < je) ? __expf(e[hh] - m[hh]) : 0.f;
            den[hh] = p[hh];
        }
        for (int off = 32; off >= 1; off >>= 1) {
#pragma unroll
            for (int hh = 0; hh < 4; hh++) den[hh] += __shfl_xor(den[hh], off, 64);
        }
        if (j < je) wp[j] = make_float4(p[0], p[1], p[2], p[3]);
        if (lane == 0)
            invden[d] = make_float4(1.f / (den[0] + 1e-16f), 1.f / (den[1] + 1e-16f),
                                    1.f / (den[2] + 1e-16f), 1.f / (den[3] + 1e-16f));
    } else {
        float m[4] = {-INFINITY, -INFINITY, -INFINITY, -INFINITY};
        for (int jj = j; jj < je; jj += 64) {
            int s = eidx[jj];
            float4 as4 = *(const float4*)(a_s + (size_t)s * 4);
#pragma unroll
            for (int hh = 0; hh < 4; hh++)
                m[hh] = fmaxf(m[hh], lrelu(((const float*)&as4)[hh] + ((const float*)&ad4)[hh]));
        }
        for (int off = 32; off >= 1; off >>= 1) {
#pragma unroll
            for (int hh = 0; hh < 4; hh++) m[hh] = fmaxf(m[hh], __shfl_xor(m[hh], off, 64));
        }
        float den[4] = {0.f, 0.f, 0.f, 0.f};
        for (int jj = j; jj < je; jj += 64) {
            int s = eidx[jj];
            float4 as4 = *(const float4*)(a_s + (size_t)s * 4);
            float p[4];
#pragma unroll
            for (int hh = 0; hh < 4; hh++) {
                float e = lrelu(((const float*)&as4)[hh] + ((const float*)&ad4)[hh]);
                p[hh] = __expf(e - m[hh]);
                den[hh] += p[hh];
            }
            wp[jj] = make_float4(p[0], p[1], p[2], p[3]);
        }
        for (int off = 32; off >= 1; off >>= 1) {
#pragma unroll
            for (int hh = 0; hh < 4; hh++) den[hh] += __shfl_xor(den[hh], off, 64);
        }
        if (lane == 0)
            invden[d] = make_float4(1.f / (den[0] + 1e-16f), 1.f / (den[1] + 1e-16f),
                                    1.f / (den[2] + 1e-16f), 1.f / (den[3] + 1e-16f));
    }
}

// ---------------- accumulation, layers 0/1 (concat): cheap serial loop ----------------
// lane handles channels 2*lane,2*lane+1 (head lane>>4). Per edge: w load + float2 gather + 2 FMA.
__global__ void k_acc01(const float* __restrict__ xp, const float* __restrict__ wp,
                        const float4* __restrict__ invden, const int* __restrict__ rowptr,
                        const int* __restrict__ eidx, const float* __restrict__ bias,
                        float* __restrict__ out, int N) {
    int d = (blockIdx.x * blockDim.x + threadIdx.x) >> 6;
    int lane = threadIdx.x & 63;
    if (d >= N) return;
    int hh = lane >> 4;
    int jb = rowptr[d], je = rowptr[d + 1];
    float a0 = 0.f, a1 = 0.f;
    for (int j = jb; j < je; ++j) {
        int s = __builtin_amdgcn_readfirstlane(eidx[j]);
        float w = wp[(size_t)j * 4 + hh];
        float2 xv = *(const float2*)(xp + (size_t)s * 128 + 2 * lane);
        a0 += w * xv.x;
        a1 += w * xv.y;
    }
    float inv = ((const float*)(invden + d))[hh];
    float2 o = make_float2(a0 * inv + bias[2 * lane], a1 * inv + bias[2 * lane + 1]);
    *(float2*)(out + (size_t)d * 128 + 2 * lane) = o;
}

// ---------------- accumulation, layer 2: 4 heads share the 128-dim h gather ----------------
__global__ void k_accL2(const float* __restrict__ hb, const float4* __restrict__ wp,
                        const float4* __restrict__ invden, const int* __restrict__ rowptr,
                        const int* __restrict__ eidx, float* __restrict__ aggbuf, int N) {
    int d = (blockIdx.x * blockDim.x + threadIdx.x) >> 6;
    int lane = threadIdx.x & 63;
    if (d >= N) return;
    int jb = rowptr[d], je = rowptr[d + 1];
    float acc[4][2] = {{0.f, 0.f}, {0.f, 0.f}, {0.f, 0.f}, {0.f, 0.f}};
    for (int j = jb; j < je; ++j) {
        int s = __builtin_amdgcn_readfirstlane(eidx[j]);
        float4 w = wp[j];  // uniform address -> broadcast
        float2 xv = *(const float2*)(hb + (size_t)s * 128 + 2 * lane);
#pragma unroll
        for (int hh = 0; hh < 4; hh++) {
            acc[hh][0] += ((const float*)&w)[hh] * xv.x;
            acc[hh][1] += ((const float*)&w)[hh] * xv.y;
        }
    }
    float4 inv = invden[d];
#pragma unroll
    for (int hh = 0; hh < 4; hh++) {
        float iv = ((const float*)&inv)[hh];
        float2 o = make_float2(acc[hh][0] * iv, acc[hh][1] * iv);
        *(float2*)(aggbuf + (size_t)d * 512 + hh * 128 + 2 * lane) = o;
    }
}

// ---------------- W2 reshuffle (folds head-mean; b2 cancelled by BN) ----------------
__global__ void k_w2p(const float* __restrict__ W2, float* __restrict__ W2p) {
    int idx = blockIdx.x * blockDim.x + threadIdx.x;
    if (idx >= 512 * 128) return;
    int j = idx >> 7, c = idx & 127;
    W2p[idx] = 0.25f * W2[(size_t)(j & 127) * 512 + (j >> 7) * 128 + c];
}

// ---------------- batch norm ----------------
__global__ void k_bnstats(const float* __restrict__ x, float* __restrict__ sums, int N) {
    int col = threadIdx.x & 127, half = threadIdx.x >> 7;
    float s1 = 0.f, s2 = 0.f;
    for (int r = blockIdx.x * 2 + half; r < N; r += gridDim.x * 2) {
        float v = x[(size_t)r * 128 + col];
        s1 += v;
        s2 += v * v;
    }
    atomicAdd(&sums[col], s1);
    atomicAdd(&sums[128 + col], s2);
}

__global__ void k_bnapply(float* __restrict__ x, const float* __restrict__ sums,
                          const float* __restrict__ gamma, const float* __restrict__ beta,
                          int N, int elu) {
    int idx = blockIdx.x * blockDim.x + threadIdx.x;  // float4 index
    if (idx >= N * 32) return;
    float4 v = ((float4*)x)[idx];
    int colb = (idx & 31) * 4;
    float invN = 1.f / (float)N;
#pragma unroll
    for (int j = 0; j < 4; j++) {
        int col = colb + j;
        float mu = sums[col] * invN;
        float var = sums[128 + col] * invN - mu * mu;
        float y = (((float*)&v)[j] - mu) * rsqrtf(var + EPS_BN) * gamma[col] + beta[col];
        if (elu) y = y > 0.f ? y : __expf(y) - 1.f;
        ((float*)&v)[j] = y;
    }
    ((float4*)x)[idx] = v;
}

// ---------------- launch ----------------
extern "C" void kernel_launch(void* const* d_in, const int* in_sizes, int n_in,
                              void* d_out, int out_size, void* d_ws, size_t ws_size,
                              hipStream_t stream) {
    const float* x = (const float*)d_in[0];
    const int* ei_raw = (const int*)d_in[1];
    const float* W0 = (const float*)d_in[2];
    const float* as0 = (const float*)d_in[3];
    const float* ad0 = (const float*)d_in[4];
    const float* b0 = (const float*)d_in[5];
    const float* g0 = (const float*)d_in[6];
    const float* be0 = (const float*)d_in[7];
    const float* W1 = (const float*)d_in[8];
    const float* as1 = (const float*)d_in[9];
    const float* ad1 = (const float*)d_in[10];
    const float* b1 = (const float*)d_in[11];
    const float* g1 = (const float*)d_in[12];
    const float* be1 = (const float*)d_in[13];
    const float* W2 = (const float*)d_in[14];
    const float* as2 = (const float*)d_in[15];
    const float* ad2 = (const float*)d_in[16];
    const float* g2v = (const float*)d_in[18];
    const float* be2 = (const float*)d_in[19];

    const int N = in_sizes[0] / 128;
    const int E = in_sizes[1] / 2;

    // workspace carve (256B aligned)
    char* p = (char*)d_ws;
    auto alloc = [&](size_t bytes) {
        void* r = (void*)p;
        p += (bytes + 255) & ~(size_t)255;
        return r;
    };
    float* xp = (float*)alloc((size_t)N * 512 * 4);    // layers 0/1: xp (N*128); layer 2: aggbuf (N*512)
    float* hbuf = (float*)alloc((size_t)N * 128 * 4);
    float* As = (float*)alloc((size_t)N * 4 * 4);
    float* Ad = (float*)alloc((size_t)N * 4 * 4);
    int* deg = (int*)alloc((size_t)N * 4);
    int* rowptr = (int*)alloc((size_t)(N + 1) * 4);
    int* cursor = (int*)alloc((size_t)N * 4);
    int* bsum = (int*)alloc(1024);
    int* eidx = (int*)alloc((size_t)(E + N) * 4);
    float* bns = (float*)alloc(256 * 4);
    // union: ei32 (2E ints) only lives through CSR build; wp ((E+N) float4) written after.
    size_t uni_bytes = (size_t)(E + N) * 16;
    size_t ei_bytes = (size_t)2 * E * 4;
    char* uni = (char*)alloc(uni_bytes > ei_bytes ? uni_bytes : ei_bytes);
    int* ei32 = (int*)uni;
    float4* wp = (float4*)uni;
    float4* invden = (float4*)alloc((size_t)N * 16);
    int* flag = (int*)alloc(256);
    float* Wt = (float*)alloc(1024 * 4);
    float* W2p = (float*)alloc((size_t)512 * 128 * 4);
    if ((size_t)(p - (char*)d_ws) > ws_size) return;

    const int nb = (N + 255) / 256;
    const int gw = (N + 3) / 4;  // wave-per-node kernels: 4 waves/block
    dim3 gg1((N + 63) / 64, 2);

    // --- edge dtype normalize (int64 vs int32) ---
    k_detect64<<<1, 64, 0, stream>>>(ei_raw, flag, 2 * E);
    k_convert<<<(2 * E + 255) / 256, 256, 0, stream>>>(ei_raw, flag, ei32, 2 * E);
    const int* srcv = ei32;
    const int* dstv = ei32 + E;

    // --- CSR build ---
    k_deg_init<<<nb, 256, 0, stream>>>(deg, N);
    k_deg_count<<<(E + 255) / 256, 256, 0, stream>>>(dstv, deg, E);
    k_scan1<<<nb, 256, 0, stream>>>(deg, rowptr, bsum, N);
    k_scan2<<<1, 256, 0, stream>>>(bsum, nb);
    k_scan3<<<nb, 256, 0, stream>>>(rowptr, bsum, N);
    k_cursor<<<nb, 256, 0, stream>>>(rowptr, cursor, N);
    k_scatter<<<(E + N + 255) / 256, 256, 0, stream>>>(srcv, dstv, cursor, eidx, E, N);

    // --- layer 0 ---
    k_gemm<128, 128><<<gg1, 256, 0, stream>>>(x, W0, xp, N);
    k_att32<<<gw, 256, 0, stream>>>(xp, as0, ad0, As, Ad, N);
    k_edgew<<<gw, 256, 0, stream>>>(As, Ad, rowptr, eidx, wp, invden, N);
    k_acc01<<<gw, 256, 0, stream>>>(xp, (const float*)wp, invden, rowptr, eidx, b0, hbuf, N);
    hipMemsetAsync(bns, 0, 256 * 4, stream);
    k_bnstats<<<256, 256, 0, stream>>>(hbuf, bns, N);
    k_bnapply<<<(N * 32 + 255) / 256, 256, 0, stream>>>(hbuf, bns, g0, be0, N, 1);

    // --- layer 1 ---
    k_gemm<128, 128><<<gg1, 256, 0, stream>>>(hbuf, W1, xp, N);
    k_att32<<<gw, 256, 0, stream>>>(xp, as1, ad1, As, Ad, N);
    k_edgew<<<gw, 256, 0, stream>>>(As, Ad, rowptr, eidx, wp, invden, N);
    k_acc01<<<gw, 256, 0, stream>>>(xp, (const float*)wp, invden, rowptr, eidx, b1, hbuf, N);
    hipMemsetAsync(bns, 0, 256 * 4, stream);
    k_bnstats<<<256, 256, 0, stream>>>(hbuf, bns, N);
    k_bnapply<<<(N * 32 + 255) / 256, 256, 0, stream>>>(hbuf, bns, g1, be1, N, 1);

    // --- layer 2 (linearity trick: aggregate h per head, then one [N,512]@[512,128] GEMM) ---
    float* outf = (float*)d_out;
    k_makeWt<<<256, 256, 0, stream>>>(W2, as2, ad2, Wt);
    k_w2p<<<(512 * 128 + 255) / 256, 256, 0, stream>>>(W2, W2p);
    k_attW<<<gw, 256, 0, stream>>>(hbuf, Wt, As, Ad, N);
    k_edgew<<<gw, 256, 0, stream>>>(As, Ad, rowptr, eidx, wp, invden, N);
    k_accL2<<<gw, 256, 0, stream>>>(hbuf, wp, invden, rowptr, eidx, xp, N);
    k_gemm<128, 512><<<gg1, 256, 0, stream>>>(xp, W2p, outf, N);
    hipMemsetAsync(bns, 0, 256 * 4, stream);
    k_bnstats<<<256, 256, 0, stream>>>(outf, bns, N);
    k_bnapply<<<(N * 32 + 255) / 256, 256, 0, stream>>>(outf, bns, g2v, be2, N, 0);
}

// Round 5
// 893.497 us; speedup vs baseline: 1.0773x; 1.0773x over previous
//
#include <hip/hip_runtime.h>
#include <math.h>

#define EPS_BN 1e-5f

typedef __bf16 bf16x8 __attribute__((ext_vector_type(8)));
typedef float floatx4 __attribute__((ext_vector_type(4)));

__device__ __forceinline__ float lrelu(float x) { return x > 0.f ? x : 0.2f * x; }

// fp32 -> bf16 (RNE) bit pattern
__device__ __forceinline__ unsigned short f2b(float f) {
    unsigned int b = __float_as_uint(f);
    b = (b + 0x7fffu + ((b >> 16) & 1u)) >> 16;
    return (unsigned short)b;
}

// ---------------- edge dtype probe (parallel) + convert ----------------
__global__ void k_detect64(const int* __restrict__ ei, int* flag, int nwords) {
    int lane = threadIdx.x;  // 64
    int lim = nwords < 512 ? nwords : 512;
    int zeros = 0;
    for (int i = 2 * lane + 1; i < lim; i += 128) zeros += (ei[i] == 0);
    for (int off = 32; off >= 1; off >>= 1) zeros += __shfl_xor(zeros, off, 64);
    if (lane == 0) *flag = (zeros > lim / 8) ? 1 : 0;
}

__global__ void k_convert(const int* __restrict__ ei, const int* __restrict__ flag,
                          int* __restrict__ out, int n) {
    int i = blockIdx.x * blockDim.x + threadIdx.x;
    int f = *flag;  // uniform
    if (i < n) out[i] = f ? ei[2 * i] : ei[i];
}

// ---------------- CSR build ----------------
__global__ void k_deg_count(const int* __restrict__ dst, int* deg, int E) {
    int i = blockIdx.x * blockDim.x + threadIdx.x;
    if (i < E) atomicAdd(&deg[dst[i]], 1);
}

// +1 inside scan accounts for the self loop (deg[] holds only real in-edges)
__global__ void k_scan1(const int* __restrict__ deg, int* rowptr, int* bsum, int N) {
    __shared__ int lds[256];
    int t = threadIdx.x, n = blockIdx.x * 256 + t;
    int v = (n < N) ? deg[n] + 1 : 0;
    int xv = v;
    lds[t] = xv;
    __syncthreads();
    for (int off = 1; off < 256; off <<= 1) {
        int tmp = (t >= off) ? lds[t - off] : 0;
        __syncthreads();
        xv += tmp;
        lds[t] = xv;
        __syncthreads();
    }
    if (n < N) rowptr[n + 1] = xv;
    if (t == 255) bsum[blockIdx.x] = xv;
}

__global__ void k_scan2(int* bsum, int nb) {
    __shared__ int lds[256];
    int t = threadIdx.x;
    int v = (t < nb) ? bsum[t] : 0;
    int xv = v;
    lds[t] = xv;
    __syncthreads();
    for (int off = 1; off < 256; off <<= 1) {
        int tmp = (t >= off) ? lds[t - off] : 0;
        __syncthreads();
        xv += tmp;
        lds[t] = xv;
        __syncthreads();
    }
    if (t < nb) bsum[t] = xv - v;  // exclusive
}

__global__ void k_scan3(int* rowptr, const int* __restrict__ bsum, int N) {
    int n = blockIdx.x * 256 + threadIdx.x;
    if (n < N) rowptr[n + 1] += bsum[blockIdx.x];
    if (n == 0) rowptr[0] = 0;
}

__global__ void k_cursor(const int* __restrict__ rowptr, int* cursor, int N) {
    int n = blockIdx.x * blockDim.x + threadIdx.x;
    if (n < N) cursor[n] = rowptr[n];
}

__global__ void k_scatter(const int* __restrict__ src, const int* __restrict__ dst,
                          int* cursor, int* eidx, int E, int N) {
    int i = blockIdx.x * blockDim.x + threadIdx.x;
    if (i < E) {
        int s = src[i], d = dst[i];
        int pos = atomicAdd(&cursor[d], 1);
        eidx[pos] = s;
    } else if (i < E + N) {
        int n_ = i - E;
        int pos = atomicAdd(&cursor[n_], 1);
        eidx[pos] = n_;  // self loop
    }
}

// ---------------- fp32 -> bf16 cast (4 elems/thread) ----------------
__global__ void k_f2b4(const float* __restrict__ in, unsigned short* __restrict__ out, int n4) {
    int i = blockIdx.x * blockDim.x + threadIdx.x;
    if (i >= n4) return;
    float4 v = ((const float4*)in)[i];
    ushort4 o = make_ushort4(f2b(v.x), f2b(v.y), f2b(v.z), f2b(v.w));
    ((ushort4*)out)[i] = o;
}

// ---------------- weight convert+transpose: WT[c][k] = scale * W[k][c] ----------------
__global__ void k_wcvt(const float* __restrict__ W, unsigned short* __restrict__ WT,
                       int K, int M) {
    int idx = blockIdx.x * blockDim.x + threadIdx.x;
    if (idx >= K * M) return;
    int c = idx / K, k = idx - c * K;
    WT[idx] = f2b(W[(size_t)k * M + c]);
}

// W2 special: WT2[c][j] = 0.25*W2[(j&127)*512 + (j>>7)*128 + c]  (j = h*128+k; folds head-mean)
__global__ void k_w2cvt(const float* __restrict__ W2, unsigned short* __restrict__ WT2) {
    int idx = blockIdx.x * blockDim.x + threadIdx.x;
    if (idx >= 128 * 512) return;
    int c = idx >> 9, j = idx & 511;
    WT2[idx] = f2b(0.25f * W2[(size_t)(j & 127) * 512 + (j >> 7) * 128 + c]);
}

// ---------------- MFMA GEMM: out[N,128] = A16[N,K] @ W (via WT[128][K]), LDS-free ----------------
// one wave per 16 rows x 128 cols; 16x16x32 bf16 MFMA; 8 col-tiles.
template <int K>
__global__ __launch_bounds__(256) void k_mgemm(const unsigned short* __restrict__ A,
                                               const unsigned short* __restrict__ WT,
                                               float* __restrict__ out, int N) {
    int gw = (blockIdx.x * 256 + threadIdx.x) >> 6;
    int lane = threadIdx.x & 63;
    int l16 = lane & 15, quad = lane >> 4;
    int row0 = gw * 16;
    if (row0 >= N) return;
    int arow = min(row0 + l16, N - 1);
    floatx4 acc[8];
#pragma unroll
    for (int c = 0; c < 8; c++) acc[c] = (floatx4){0.f, 0.f, 0.f, 0.f};
    const unsigned short* Ap = A + (size_t)arow * K + quad * 8;
#pragma unroll 4
    for (int k0 = 0; k0 < K; k0 += 32) {
        bf16x8 af = *(const bf16x8*)(Ap + k0);
#pragma unroll
        for (int c = 0; c < 8; c++) {
            bf16x8 bf = *(const bf16x8*)(WT + (size_t)(c * 16 + l16) * K + k0 + quad * 8);
            acc[c] = __builtin_amdgcn_mfma_f32_16x16x32_bf16(af, bf, acc[c], 0, 0, 0);
        }
    }
#pragma unroll
    for (int c = 0; c < 8; c++) {
#pragma unroll
        for (int r = 0; r < 4; r++) {
            int row = row0 + quad * 4 + r;
            if (row < N) out[(size_t)row * 128 + c * 16 + l16] = acc[c][r];
        }
    }
}

// ---------------- attention scores, layers 0/1 ----------------
__global__ void k_att32(const float* __restrict__ xp, const float* __restrict__ att_s,
                        const float* __restrict__ att_d, float* __restrict__ a_s,
                        float* __restrict__ a_d, int N) {
    int wid = (blockIdx.x * blockDim.x + threadIdx.x) >> 6;
    int lane = threadIdx.x & 63;
    if (wid >= N) return;
    const float* xr = xp + (size_t)wid * 128;
    float x0 = xr[lane], x1 = xr[lane + 64];
    float ps0 = x0 * att_s[lane], ps1 = x1 * att_s[lane + 64];
    float pd0 = x0 * att_d[lane], pd1 = x1 * att_d[lane + 64];
    for (int m = 16; m >= 1; m >>= 1) {
        ps0 += __shfl_xor(ps0, m, 64);
        ps1 += __shfl_xor(ps1, m, 64);
        pd0 += __shfl_xor(pd0, m, 64);
        pd1 += __shfl_xor(pd1, m, 64);
    }
    if ((lane & 31) == 0) {
        int h = lane >> 5;
        a_s[wid * 4 + h] = ps0;
        a_s[wid * 4 + 2 + h] = ps1;
        a_d[wid * 4 + h] = pd0;
        a_d[wid * 4 + 2 + h] = pd1;
    }
}

// ---------------- layer 2 score precompute ----------------
__global__ void k_makeWt(const float* __restrict__ W2, const float* __restrict__ as2,
                         const float* __restrict__ ad2, float* __restrict__ Wt) {
    int wid = (blockIdx.x * blockDim.x + threadIdx.x) >> 6;
    int lane = threadIdx.x & 63;
    if (wid >= 1024) return;
    int k = wid & 127, hh = (wid >> 7) & 3, isd = wid >> 9;
    const float* att = isd ? ad2 : as2;
    float v = W2[(size_t)k * 512 + hh * 128 + lane] * att[hh * 128 + lane] +
              W2[(size_t)k * 512 + hh * 128 + 64 + lane] * att[hh * 128 + 64 + lane];
    for (int m = 32; m >= 1; m >>= 1) v += __shfl_xor(v, m, 64);
    if (lane == 0) Wt[isd * 512 + hh * 128 + k] = v;
}

// ---------------- layer 2 scores from h ----------------
__global__ void k_attW(const float* __restrict__ hb, const float* __restrict__ Wt,
                       float* __restrict__ a_s, float* __restrict__ a_d, int N) {
    int wid = (blockIdx.x * blockDim.x + threadIdx.x) >> 6;
    int lane = threadIdx.x & 63;
    if (wid >= N) return;
    float x0 = hb[(size_t)wid * 128 + lane], x1 = hb[(size_t)wid * 128 + 64 + lane];
    float ts[4], td[4];
#pragma unroll
    for (int hh = 0; hh < 4; hh++) {
        ts[hh] = x0 * Wt[hh * 128 + lane] + x1 * Wt[hh * 128 + 64 + lane];
        td[hh] = x0 * Wt[512 + hh * 128 + lane] + x1 * Wt[512 + hh * 128 + 64 + lane];
    }
    for (int m = 32; m >= 1; m >>= 1) {
#pragma unroll
        for (int hh = 0; hh < 4; hh++) {
            ts[hh] += __shfl_xor(ts[hh], m, 64);
            td[hh] += __shfl_xor(td[hh], m, 64);
        }
    }
    if (lane == 0) {
#pragma unroll
        for (int hh = 0; hh < 4; hh++) {
            a_s[wid * 4 + hh] = ts[hh];
            a_d[wid * 4 + hh] = td[hh];
        }
    }
}

// ---------------- edge softmax weights ----------------
__global__ void k_edgew(const float* __restrict__ a_s, const float* __restrict__ a_d,
                        const int* __restrict__ rowptr, const int* __restrict__ eidx,
                        float4* __restrict__ wp, float4* __restrict__ invden, int N) {
    int d = (blockIdx.x * blockDim.x + threadIdx.x) >> 6;
    int lane = threadIdx.x & 63;
    if (d >= N) return;
    float4 ad4 = *(const float4*)(a_d + (size_t)d * 4);
    int jb = rowptr[d], je = rowptr[d + 1], deg = je - jb;
    int j = jb + lane;
    if (deg <= 64) {
        float e[4] = {-INFINITY, -INFINITY, -INFINITY, -INFINITY};
        if (j < je) {
            int s = eidx[j];
            float4 as4 = *(const float4*)(a_s + (size_t)s * 4);
#pragma unroll
            for (int hh = 0; hh < 4; hh++)
                e[hh] = lrelu(((const float*)&as4)[hh] + ((const float*)&ad4)[hh]);
        }
        float m[4] = {e[0], e[1], e[2], e[3]};
        for (int off = 32; off >= 1; off >>= 1) {
#pragma unroll
            for (int hh = 0; hh < 4; hh++) m[hh] = fmaxf(m[hh], __shfl_xor(m[hh], off, 64));
        }
        float p[4], den[4];
#pragma unroll
        for (int hh = 0; hh < 4; hh++) {
            p[hh] = (j < je) ? __expf(e[hh] - m[hh]) : 0.f;
            den[hh] = p[hh];
        }
        for (int off = 32; off >= 1; off >>= 1) {
#pragma unroll
            for (int hh = 0; hh < 4; hh++) den[hh] += __shfl_xor(den[hh], off, 64);
        }
        if (j < je) wp[j] = make_float4(p[0], p[1], p[2], p[3]);
        if (lane == 0)
            invden[d] = make_float4(1.f / (den[0] + 1e-16f), 1.f / (den[1] + 1e-16f),
                                    1.f / (den[2] + 1e-16f), 1.f / (den[3] + 1e-16f));
    } else {
        float m[4] = {-INFINITY, -INFINITY, -INFINITY, -INFINITY};
        for (int jj = j; jj < je; jj += 64) {
            int s = eidx[jj];
            float4 as4 = *(const float4*)(a_s + (size_t)s * 4);
#pragma unroll
            for (int hh = 0; hh < 4; hh++)
                m[hh] = fmaxf(m[hh], lrelu(((const float*)&as4)[hh] + ((const float*)&ad4)[hh]));
        }
        for (int off = 32; off >= 1; off >>= 1) {
#pragma unroll
            for (int hh = 0; hh < 4; hh++) m[hh] = fmaxf(m[hh], __shfl_xor(m[hh], off, 64));
        }
        float den[4] = {0.f, 0.f, 0.f, 0.f};
        for (int jj = j; jj < je; jj += 64) {
            int s = eidx[jj];
            float4 as4 = *(const float4*)(a_s + (size_t)s * 4);
            float p[4];
#pragma unroll
            for (int hh = 0; hh < 4; hh++) {
                float e = lrelu(((const float*)&as4)[hh] + ((const float*)&ad4)[hh]);
                p[hh] = __expf(e - m[hh]);
                den[hh] += p[hh];
            }
            wp[jj] = make_float4(p[0], p[1], p[2], p[3]);
        }
        for (int off = 32; off >= 1; off >>= 1) {
#pragma unroll
            for (int hh = 0; hh < 4; hh++) den[hh] += __shfl_xor(den[hh], off, 64);
        }
        if (lane == 0)
            invden[d] = make_float4(1.f / (den[0] + 1e-16f), 1.f / (den[1] + 1e-16f),
                                    1.f / (den[2] + 1e-16f), 1.f / (den[3] + 1e-16f));
    }
}

// ---------------- accumulation, layers 0/1 ----------------
__global__ void k_acc01(const float* __restrict__ xp, const float* __restrict__ wp,
                        const float4* __restrict__ invden, const int* __restrict__ rowptr,
                        const int* __restrict__ eidx, const float* __restrict__ bias,
                        float* __restrict__ out, int N) {
    int d = (blockIdx.x * blockDim.x + threadIdx.x) >> 6;
    int lane = threadIdx.x & 63;
    if (d >= N) return;
    int hh = lane >> 4;
    int jb = rowptr[d], je = rowptr[d + 1];
    float a0 = 0.f, a1 = 0.f;
    for (int j = jb; j < je; ++j) {
        int s = __builtin_amdgcn_readfirstlane(eidx[j]);
        float w = wp[(size_t)j * 4 + hh];
        float2 xv = *(const float2*)(xp + (size_t)s * 128 + 2 * lane);
        a0 += w * xv.x;
        a1 += w * xv.y;
    }
    float inv = ((const float*)(invden + d))[hh];
    float2 o = make_float2(a0 * inv + bias[2 * lane], a1 * inv + bias[2 * lane + 1]);
    *(float2*)(out + (size_t)d * 128 + 2 * lane) = o;
}

// ---------------- accumulation, layer 2 -> bf16 aggregate (GEMM operand) ----------------
__global__ void k_accL2(const float* __restrict__ hb, const float4* __restrict__ wp,
                        const float4* __restrict__ invden, const int* __restrict__ rowptr,
                        const int* __restrict__ eidx, unsigned short* __restrict__ agg16,
                        int N) {
    int d = (blockIdx.x * blockDim.x + threadIdx.x) >> 6;
    int lane = threadIdx.x & 63;
    if (d >= N) return;
    int jb = rowptr[d], je = rowptr[d + 1];
    float acc[4][2] = {{0.f, 0.f}, {0.f, 0.f}, {0.f, 0.f}, {0.f, 0.f}};
    for (int j = jb; j < je; ++j) {
        int s = __builtin_amdgcn_readfirstlane(eidx[j]);
        float4 w = wp[j];
        float2 xv = *(const float2*)(hb + (size_t)s * 128 + 2 * lane);
#pragma unroll
        for (int hh = 0; hh < 4; hh++) {
            acc[hh][0] += ((const float*)&w)[hh] * xv.x;
            acc[hh][1] += ((const float*)&w)[hh] * xv.y;
        }
    }
    float4 inv = invden[d];
#pragma unroll
    for (int hh = 0; hh < 4; hh++) {
        float iv = ((const float*)&inv)[hh];
        ushort2 o = make_ushort2(f2b(acc[hh][0] * iv), f2b(acc[hh][1] * iv));
        *(ushort2*)(agg16 + (size_t)d * 512 + hh * 128 + 2 * lane) = o;
    }
}

// ---------------- batch norm ----------------
__global__ void k_bnstats(const float* __restrict__ x, float* __restrict__ sums, int N) {
    int col = threadIdx.x & 127, half = threadIdx.x >> 7;
    float s1 = 0.f, s2 = 0.f;
    for (int r = blockIdx.x * 2 + half; r < N; r += gridDim.x * 2) {
        float v = x[(size_t)r * 128 + col];
        s1 += v;
        s2 += v * v;
    }
    atomicAdd(&sums[col], s1);
    atomicAdd(&sums[128 + col], s2);
}

// normalize (+ELU) in place; optionally also emit bf16 copy for the next GEMM
__global__ void k_bnapply(float* __restrict__ x, unsigned short* __restrict__ out16,
                          const float* __restrict__ sums, const float* __restrict__ gamma,
                          const float* __restrict__ beta, int N, int elu) {
    int idx = blockIdx.x * blockDim.x + threadIdx.x;  // float4 index
    if (idx >= N * 32) return;
    float4 v = ((float4*)x)[idx];
    int colb = (idx & 31) * 4;
    float invN = 1.f / (float)N;
#pragma unroll
    for (int j = 0; j < 4; j++) {
        int col = colb + j;
        float mu = sums[col] * invN;
        float var = sums[128 + col] * invN - mu * mu;
        float y = (((float*)&v)[j] - mu) * rsqrtf(var + EPS_BN) * gamma[col] + beta[col];
        if (elu) y = y > 0.f ? y : __expf(y) - 1.f;
        ((float*)&v)[j] = y;
    }
    ((float4*)x)[idx] = v;
    if (out16) {
        ushort4 o = make_ushort4(f2b(v.x), f2b(v.y), f2b(v.z), f2b(v.w));
        ((ushort4*)out16)[idx] = o;
    }
}

// ---------------- launch ----------------
extern "C" void kernel_launch(void* const* d_in, const int* in_sizes, int n_in,
                              void* d_out, int out_size, void* d_ws, size_t ws_size,
                              hipStream_t stream) {
    const float* x = (const float*)d_in[0];
    const int* ei_raw = (const int*)d_in[1];
    const float* W0 = (const float*)d_in[2];
    const float* as0 = (const float*)d_in[3];
    const float* ad0 = (const float*)d_in[4];
    const float* b0 = (const float*)d_in[5];
    const float* g0 = (const float*)d_in[6];
    const float* be0 = (const float*)d_in[7];
    const float* W1 = (const float*)d_in[8];
    const float* as1 = (const float*)d_in[9];
    const float* ad1 = (const float*)d_in[10];
    const float* b1 = (const float*)d_in[11];
    const float* g1 = (const float*)d_in[12];
    const float* be1 = (const float*)d_in[13];
    const float* W2 = (const float*)d_in[14];
    const float* as2 = (const float*)d_in[15];
    const float* ad2 = (const float*)d_in[16];
    const float* g2v = (const float*)d_in[18];
    const float* be2 = (const float*)d_in[19];

    const int N = in_sizes[0] / 128;
    const int E = in_sizes[1] / 2;

    // workspace carve (256B aligned)
    char* p = (char*)d_ws;
    auto alloc = [&](size_t bytes) {
        void* r = (void*)p;
        p += (bytes + 255) & ~(size_t)255;
        return r;
    };
    float* xp = (float*)alloc((size_t)N * 128 * 4);      // per-layer projected features (fp32)
    float* hbuf = (float*)alloc((size_t)N * 128 * 4);    // hidden (fp32)
    unsigned short* xb = (unsigned short*)alloc((size_t)N * 128 * 2);    // bf16 of x
    unsigned short* hb16 = (unsigned short*)alloc((size_t)N * 128 * 2);  // bf16 of hbuf
    unsigned short* agg16 = (unsigned short*)alloc((size_t)N * 512 * 2); // bf16 layer-2 aggregate
    float* As = (float*)alloc((size_t)N * 4 * 4);
    float* Ad = (float*)alloc((size_t)N * 4 * 4);
    int* deg = (int*)alloc((size_t)N * 4);
    int* rowptr = (int*)alloc((size_t)(N + 1) * 4);
    int* cursor = (int*)alloc((size_t)N * 4);
    int* bsum = (int*)alloc(1024);
    int* eidx = (int*)alloc((size_t)(E + N) * 4);
    float* bns = (float*)alloc(256 * 4);
    // union: ei32 (2E ints, CSR build only) then wp ((E+N) float4)
    size_t uni_bytes = (size_t)(E + N) * 16;
    size_t ei_bytes = (size_t)2 * E * 4;
    char* uni = (char*)alloc(uni_bytes > ei_bytes ? uni_bytes : ei_bytes);
    int* ei32 = (int*)uni;
    float4* wp = (float4*)uni;
    float4* invden = (float4*)alloc((size_t)N * 16);
    int* flag = (int*)alloc(256);
    float* Wt = (float*)alloc(1024 * 4);
    unsigned short* WT0 = (unsigned short*)alloc((size_t)128 * 128 * 2);
    unsigned short* WT1 = (unsigned short*)alloc((size_t)128 * 128 * 2);
    unsigned short* WT2 = (unsigned short*)alloc((size_t)128 * 512 * 2);
    if ((size_t)(p - (char*)d_ws) > ws_size) return;

    const int nb = (N + 255) / 256;
    const int gw = (N + 3) / 4;              // wave-per-node kernels
    const int gm = (N / 16 + 3) / 4 + 1;     // mgemm: wave per 16 rows

    // --- edge dtype normalize ---
    k_detect64<<<1, 64, 0, stream>>>(ei_raw, flag, 2 * E);
    k_convert<<<(2 * E + 255) / 256, 256, 0, stream>>>(ei_raw, flag, ei32, 2 * E);
    const int* srcv = ei32;
    const int* dstv = ei32 + E;

    // --- CSR build ---
    hipMemsetAsync(deg, 0, (size_t)N * 4, stream);
    k_deg_count<<<(E + 255) / 256, 256, 0, stream>>>(dstv, deg, E);
    k_scan1<<<nb, 256, 0, stream>>>(deg, rowptr, bsum, N);
    k_scan2<<<1, 256, 0, stream>>>(bsum, nb);
    k_scan3<<<nb, 256, 0, stream>>>(rowptr, bsum, N);
    k_cursor<<<nb, 256, 0, stream>>>(rowptr, cursor, N);
    k_scatter<<<(E + N + 255) / 256, 256, 0, stream>>>(srcv, dstv, cursor, eidx, E, N);

    // --- weight prep (bf16 transposed) + input cast ---
    k_wcvt<<<(128 * 128 + 255) / 256, 256, 0, stream>>>(W0, WT0, 128, 128);
    k_wcvt<<<(128 * 128 + 255) / 256, 256, 0, stream>>>(W1, WT1, 128, 128);
    k_w2cvt<<<(128 * 512 + 255) / 256, 256, 0, stream>>>(W2, WT2);
    k_makeWt<<<256, 256, 0, stream>>>(W2, as2, ad2, Wt);
    k_f2b4<<<(N * 32 + 255) / 256, 256, 0, stream>>>(x, xb, N * 32);

    // --- layer 0 ---
    k_mgemm<128><<<gm, 256, 0, stream>>>(xb, WT0, xp, N);
    k_att32<<<gw, 256, 0, stream>>>(xp, as0, ad0, As, Ad, N);
    k_edgew<<<gw, 256, 0, stream>>>(As, Ad, rowptr, eidx, wp, invden, N);
    k_acc01<<<gw, 256, 0, stream>>>(xp, (const float*)wp, invden, rowptr, eidx, b0, hbuf, N);
    hipMemsetAsync(bns, 0, 256 * 4, stream);
    k_bnstats<<<256, 256, 0, stream>>>(hbuf, bns, N);
    k_bnapply<<<(N * 32 + 255) / 256, 256, 0, stream>>>(hbuf, hb16, bns, g0, be0, N, 1);

    // --- layer 1 ---
    k_mgemm<128><<<gm, 256, 0, stream>>>(hb16, WT1, xp, N);
    k_att32<<<gw, 256, 0, stream>>>(xp, as1, ad1, As, Ad, N);
    k_edgew<<<gw, 256, 0, stream>>>(As, Ad, rowptr, eidx, wp, invden, N);
    k_acc01<<<gw, 256, 0, stream>>>(xp, (const float*)wp, invden, rowptr, eidx, b1, hbuf, N);
    hipMemsetAsync(bns, 0, 256 * 4, stream);
    k_bnstats<<<256, 256, 0, stream>>>(hbuf, bns, N);
    k_bnapply<<<(N * 32 + 255) / 256, 256, 0, stream>>>(hbuf, hb16, bns, g1, be1, N, 1);

    // --- layer 2 (linearity: aggregate h per head, then [N,512]@[512,128] MFMA GEMM) ---
    float* outf = (float*)d_out;
    k_attW<<<gw, 256, 0, stream>>>(hbuf, Wt, As, Ad, N);
    k_edgew<<<gw, 256, 0, stream>>>(As, Ad, rowptr, eidx, wp, invden, N);
    k_accL2<<<gw, 256, 0, stream>>>(hbuf, wp, invden, rowptr, eidx, agg16, N);
    k_mgemm<512><<<gm, 256, 0, stream>>>(agg16, WT2, outf, N);
    hipMemsetAsync(bns, 0, 256 * 4, stream);
    k_bnstats<<<256, 256, 0, stream>>>(outf, bns, N);
    k_bnapply<<<(N * 32 + 255) / 256, 256, 0, stream>>>(outf, (unsigned short*)nullptr, bns, g2v, be2, N, 0);
}

// Round 6
// 754.293 us; speedup vs baseline: 1.2761x; 1.1845x over previous
//
#include <hip/hip_runtime.h>
#include <math.h>

#define EPS_BN 1e-5f

typedef __bf16 bf16x8 __attribute__((ext_vector_type(8)));
typedef float floatx4 __attribute__((ext_vector_type(4)));

__device__ __forceinline__ float lrelu(float x) { return x > 0.f ? x : 0.2f * x; }

// fp32 -> bf16 (RNE) bit pattern
__device__ __forceinline__ unsigned short f2b(float f) {
    unsigned int b = __float_as_uint(f);
    b = (b + 0x7fffu + ((b >> 16) & 1u)) >> 16;
    return (unsigned short)b;
}
// packed ushort2(bf16x2) -> two floats
__device__ __forceinline__ float b2f_lo(unsigned int u) { return __uint_as_float(u << 16); }
__device__ __forceinline__ float b2f_hi(unsigned int u) { return __uint_as_float(u & 0xffff0000u); }

// ---------------- edge dtype probe (parallel) + convert ----------------
__global__ void k_detect64(const int* __restrict__ ei, int* flag, int nwords) {
    int lane = threadIdx.x;  // 64
    int lim = nwords < 512 ? nwords : 512;
    int zeros = 0;
    for (int i = 2 * lane + 1; i < lim; i += 128) zeros += (ei[i] == 0);
    for (int off = 32; off >= 1; off >>= 1) zeros += __shfl_xor(zeros, off, 64);
    if (lane == 0) *flag = (zeros > lim / 8) ? 1 : 0;
}

__global__ void k_convert(const int* __restrict__ ei, const int* __restrict__ flag,
                          int* __restrict__ out, int n) {
    int i = blockIdx.x * blockDim.x + threadIdx.x;
    int f = *flag;  // uniform
    if (i < n) out[i] = f ? ei[2 * i] : ei[i];
}

// ---------------- CSR build ----------------
__global__ void k_deg_count(const int* __restrict__ dst, int* deg, int E) {
    int i = blockIdx.x * blockDim.x + threadIdx.x;
    if (i < E) atomicAdd(&deg[dst[i]], 1);
}

// +1 inside scan accounts for the self loop (deg[] holds only real in-edges)
__global__ void k_scan1(const int* __restrict__ deg, int* rowptr, int* bsum, int N) {
    __shared__ int lds[256];
    int t = threadIdx.x, n = blockIdx.x * 256 + t;
    int v = (n < N) ? deg[n] + 1 : 0;
    int xv = v;
    lds[t] = xv;
    __syncthreads();
    for (int off = 1; off < 256; off <<= 1) {
        int tmp = (t >= off) ? lds[t - off] : 0;
        __syncthreads();
        xv += tmp;
        lds[t] = xv;
        __syncthreads();
    }
    if (n < N) rowptr[n + 1] = xv;
    if (t == 255) bsum[blockIdx.x] = xv;
}

__global__ void k_scan2(int* bsum, int nb) {
    __shared__ int lds[256];
    int t = threadIdx.x;
    int v = (t < nb) ? bsum[t] : 0;
    int xv = v;
    lds[t] = xv;
    __syncthreads();
    for (int off = 1; off < 256; off <<= 1) {
        int tmp = (t >= off) ? lds[t - off] : 0;
        __syncthreads();
        xv += tmp;
        lds[t] = xv;
        __syncthreads();
    }
    if (t < nb) bsum[t] = xv - v;  // exclusive
}

__global__ void k_scan3(int* rowptr, const int* __restrict__ bsum, int N) {
    int n = blockIdx.x * 256 + threadIdx.x;
    if (n < N) rowptr[n + 1] += bsum[blockIdx.x];
    if (n == 0) rowptr[0] = 0;
}

__global__ void k_cursor(const int* __restrict__ rowptr, int* cursor, int N) {
    int n = blockIdx.x * blockDim.x + threadIdx.x;
    if (n < N) cursor[n] = rowptr[n];
}

__global__ void k_scatter(const int* __restrict__ src, const int* __restrict__ dst,
                          int* cursor, int* eidx, int E, int N) {
    int i = blockIdx.x * blockDim.x + threadIdx.x;
    if (i < E) {
        int s = src[i], d = dst[i];
        int pos = atomicAdd(&cursor[d], 1);
        eidx[pos] = s;
    } else if (i < E + N) {
        int n_ = i - E;
        int pos = atomicAdd(&cursor[n_], 1);
        eidx[pos] = n_;  // self loop
    }
}

// ---------------- fp32 -> bf16 cast (4 elems/thread) ----------------
__global__ void k_f2b4(const float* __restrict__ in, unsigned short* __restrict__ out, int n4) {
    int i = blockIdx.x * blockDim.x + threadIdx.x;
    if (i >= n4) return;
    float4 v = ((const float4*)in)[i];
    ushort4 o = make_ushort4(f2b(v.x), f2b(v.y), f2b(v.z), f2b(v.w));
    ((ushort4*)out)[i] = o;
}

// ---------------- weight convert+transpose: WT[c][k] = W[k][c] ----------------
__global__ void k_wcvt(const float* __restrict__ W, unsigned short* __restrict__ WT,
                       int K, int M) {
    int idx = blockIdx.x * blockDim.x + threadIdx.x;
    if (idx >= K * M) return;
    int c = idx / K, k = idx - c * K;
    WT[idx] = f2b(W[(size_t)k * M + c]);
}

// W2 special: WT2[c][j] = 0.25*W2[(j&127)*512 + (j>>7)*128 + c]  (j = h*128+k; folds head-mean)
__global__ void k_w2cvt(const float* __restrict__ W2, unsigned short* __restrict__ WT2) {
    int idx = blockIdx.x * blockDim.x + threadIdx.x;
    if (idx >= 128 * 512) return;
    int c = idx >> 9, j = idx & 511;
    WT2[idx] = f2b(0.25f * W2[(size_t)(j & 127) * 512 + (j >> 7) * 128 + c]);
}

// ---------------- MFMA GEMM: out[N,128] = A16[N,K] @ W (via WT[128][K]), LDS-free ----------------
// one wave per 16 rows x 128 cols; 16x16x32 bf16 MFMA; 8 col-tiles. Optional bf16 dual-write.
template <int K>
__global__ __launch_bounds__(256) void k_mgemm(const unsigned short* __restrict__ A,
                                               const unsigned short* __restrict__ WT,
                                               float* __restrict__ out,
                                               unsigned short* __restrict__ out16, int N) {
    int gw = (blockIdx.x * 256 + threadIdx.x) >> 6;
    int lane = threadIdx.x & 63;
    int l16 = lane & 15, quad = lane >> 4;
    int row0 = gw * 16;
    if (row0 >= N) return;
    int arow = min(row0 + l16, N - 1);
    floatx4 acc[8];
#pragma unroll
    for (int c = 0; c < 8; c++) acc[c] = (floatx4){0.f, 0.f, 0.f, 0.f};
    const unsigned short* Ap = A + (size_t)arow * K + quad * 8;
#pragma unroll 4
    for (int k0 = 0; k0 < K; k0 += 32) {
        bf16x8 af = *(const bf16x8*)(Ap + k0);
#pragma unroll
        for (int c = 0; c < 8; c++) {
            bf16x8 bf = *(const bf16x8*)(WT + (size_t)(c * 16 + l16) * K + k0 + quad * 8);
            acc[c] = __builtin_amdgcn_mfma_f32_16x16x32_bf16(af, bf, acc[c], 0, 0, 0);
        }
    }
#pragma unroll
    for (int c = 0; c < 8; c++) {
#pragma unroll
        for (int r = 0; r < 4; r++) {
            int row = row0 + quad * 4 + r;
            if (row < N) {
                out[(size_t)row * 128 + c * 16 + l16] = acc[c][r];
                if (out16) out16[(size_t)row * 128 + c * 16 + l16] = f2b(acc[c][r]);
            }
        }
    }
}

// ---------------- attention scores, layers 0/1 ----------------
__global__ void k_att32(const float* __restrict__ xp, const float* __restrict__ att_s,
                        const float* __restrict__ att_d, float* __restrict__ a_s,
                        float* __restrict__ a_d, int N) {
    int wid = (blockIdx.x * blockDim.x + threadIdx.x) >> 6;
    int lane = threadIdx.x & 63;
    if (wid >= N) return;
    const float* xr = xp + (size_t)wid * 128;
    float x0 = xr[lane], x1 = xr[lane + 64];
    float ps0 = x0 * att_s[lane], ps1 = x1 * att_s[lane + 64];
    float pd0 = x0 * att_d[lane], pd1 = x1 * att_d[lane + 64];
    for (int m = 16; m >= 1; m >>= 1) {
        ps0 += __shfl_xor(ps0, m, 64);
        ps1 += __shfl_xor(ps1, m, 64);
        pd0 += __shfl_xor(pd0, m, 64);
        pd1 += __shfl_xor(pd1, m, 64);
    }
    if ((lane & 31) == 0) {
        int h = lane >> 5;
        a_s[wid * 4 + h] = ps0;
        a_s[wid * 4 + 2 + h] = ps1;
        a_d[wid * 4 + h] = pd0;
        a_d[wid * 4 + 2 + h] = pd1;
    }
}

// ---------------- layer 2 score precompute ----------------
__global__ void k_makeWt(const float* __restrict__ W2, const float* __restrict__ as2,
                         const float* __restrict__ ad2, float* __restrict__ Wt) {
    int wid = (blockIdx.x * blockDim.x + threadIdx.x) >> 6;
    int lane = threadIdx.x & 63;
    if (wid >= 1024) return;
    int k = wid & 127, hh = (wid >> 7) & 3, isd = wid >> 9;
    const float* att = isd ? ad2 : as2;
    float v = W2[(size_t)k * 512 + hh * 128 + lane] * att[hh * 128 + lane] +
              W2[(size_t)k * 512 + hh * 128 + 64 + lane] * att[hh * 128 + 64 + lane];
    for (int m = 32; m >= 1; m >>= 1) v += __shfl_xor(v, m, 64);
    if (lane == 0) Wt[isd * 512 + hh * 128 + k] = v;
}

// ---------------- layer 2 scores from h ----------------
__global__ void k_attW(const float* __restrict__ hb, const float* __restrict__ Wt,
                       float* __restrict__ a_s, float* __restrict__ a_d, int N) {
    int wid = (blockIdx.x * blockDim.x + threadIdx.x) >> 6;
    int lane = threadIdx.x & 63;
    if (wid >= N) return;
    float x0 = hb[(size_t)wid * 128 + lane], x1 = hb[(size_t)wid * 128 + 64 + lane];
    float ts[4], td[4];
#pragma unroll
    for (int hh = 0; hh < 4; hh++) {
        ts[hh] = x0 * Wt[hh * 128 + lane] + x1 * Wt[hh * 128 + 64 + lane];
        td[hh] = x0 * Wt[512 + hh * 128 + lane] + x1 * Wt[512 + hh * 128 + 64 + lane];
    }
    for (int m = 32; m >= 1; m >>= 1) {
#pragma unroll
        for (int hh = 0; hh < 4; hh++) {
            ts[hh] += __shfl_xor(ts[hh], m, 64);
            td[hh] += __shfl_xor(td[hh], m, 64);
        }
    }
    if (lane == 0) {
#pragma unroll
        for (int hh = 0; hh < 4; hh++) {
            a_s[wid * 4 + hh] = ts[hh];
            a_d[wid * 4 + hh] = td[hh];
        }
    }
}

// ---------------- edge softmax weights ----------------
__global__ void k_edgew(const float* __restrict__ a_s, const float* __restrict__ a_d,
                        const int* __restrict__ rowptr, const int* __restrict__ eidx,
                        float4* __restrict__ wp, float4* __restrict__ invden, int N) {
    int d = (blockIdx.x * blockDim.x + threadIdx.x) >> 6;
    int lane = threadIdx.x & 63;
    if (d >= N) return;
    float4 ad4 = *(const float4*)(a_d + (size_t)d * 4);
    int jb = rowptr[d], je = rowptr[d + 1], deg = je - jb;
    int j = jb + lane;
    if (deg <= 64) {
        float e[4] = {-INFINITY, -INFINITY, -INFINITY, -INFINITY};
        if (j < je) {
            int s = eidx[j];
            float4 as4 = *(const float4*)(a_s + (size_t)s * 4);
#pragma unroll
            for (int hh = 0; hh < 4; hh++)
                e[hh] = lrelu(((const float*)&as4)[hh] + ((const float*)&ad4)[hh]);
        }
        float m[4] = {e[0], e[1], e[2], e[3]};
        for (int off = 32; off >= 1; off >>= 1) {
#pragma unroll
            for (int hh = 0; hh < 4; hh++) m[hh] = fmaxf(m[hh], __shfl_xor(m[hh], off, 64));
        }
        float p[4], den[4];
#pragma unroll
        for (int hh = 0; hh < 4; hh++) {
            p[hh] = (j < je) ? __expf(e[hh] - m[hh]) : 0.f;
            den[hh] = p[hh];
        }
        for (int off = 32; off >= 1; off >>= 1) {
#pragma unroll
            for (int hh = 0; hh < 4; hh++) den[hh] += __shfl_xor(den[hh], off, 64);
        }
        if (j < je) wp[j] = make_float4(p[0], p[1], p[2], p[3]);
        if (lane == 0)
            invden[d] = make_float4(1.f / (den[0] + 1e-16f), 1.f / (den[1] + 1e-16f),
                                    1.f / (den[2] + 1e-16f), 1.f / (den[3] + 1e-16f));
    } else {
        float m[4] = {-INFINITY, -INFINITY, -INFINITY, -INFINITY};
        for (int jj = j; jj < je; jj += 64) {
            int s = eidx[jj];
            float4 as4 = *(const float4*)(a_s + (size_t)s * 4);
#pragma unroll
            for (int hh = 0; hh < 4; hh++)
                m[hh] = fmaxf(m[hh], lrelu(((const float*)&as4)[hh] + ((const float*)&ad4)[hh]));
        }
        for (int off = 32; off >= 1; off >>= 1) {
#pragma unroll
            for (int hh = 0; hh < 4; hh++) m[hh] = fmaxf(m[hh], __shfl_xor(m[hh], off, 64));
        }
        float den[4] = {0.f, 0.f, 0.f, 0.f};
        for (int jj = j; jj < je; jj += 64) {
            int s = eidx[jj];
            float4 as4 = *(const float4*)(a_s + (size_t)s * 4);
            float p[4];
#pragma unroll
            for (int hh = 0; hh < 4; hh++) {
                float e = lrelu(((const float*)&as4)[hh] + ((const float*)&ad4)[hh]);
                p[hh] = __expf(e - m[hh]);
                den[hh] += p[hh];
            }
            wp[jj] = make_float4(p[0], p[1], p[2], p[3]);
        }
        for (int off = 32; off >= 1; off >>= 1) {
#pragma unroll
            for (int hh = 0; hh < 4; hh++) den[hh] += __shfl_xor(den[hh], off, 64);
        }
        if (lane == 0)
            invden[d] = make_float4(1.f / (den[0] + 1e-16f), 1.f / (den[1] + 1e-16f),
                                    1.f / (den[2] + 1e-16f), 1.f / (den[3] + 1e-16f));
    }
}

// ---------------- accumulation, layers 0/1: bf16 gather, unroll x4 for MLP ----------------
// lane handles channels 2*lane,2*lane+1 (head lane>>4).
__global__ void k_acc01(const unsigned short* __restrict__ xp16, const float* __restrict__ wp,
                        const float4* __restrict__ invden, const int* __restrict__ rowptr,
                        const int* __restrict__ eidx, const float* __restrict__ bias,
                        float* __restrict__ out, int N) {
    int d = (blockIdx.x * blockDim.x + threadIdx.x) >> 6;
    int lane = threadIdx.x & 63;
    if (d >= N) return;
    int hh = lane >> 4;
    int jb = rowptr[d], je = rowptr[d + 1];
    float a0 = 0.f, a1 = 0.f;
    int j = jb;
    for (; j + 4 <= je; j += 4) {
        int s0 = __builtin_amdgcn_readfirstlane(eidx[j]);
        int s1 = __builtin_amdgcn_readfirstlane(eidx[j + 1]);
        int s2 = __builtin_amdgcn_readfirstlane(eidx[j + 2]);
        int s3 = __builtin_amdgcn_readfirstlane(eidx[j + 3]);
        float w0 = wp[(size_t)j * 4 + hh];
        float w1 = wp[(size_t)(j + 1) * 4 + hh];
        float w2 = wp[(size_t)(j + 2) * 4 + hh];
        float w3 = wp[(size_t)(j + 3) * 4 + hh];
        unsigned int u0 = *(const unsigned int*)(xp16 + (size_t)s0 * 128 + 2 * lane);
        unsigned int u1 = *(const unsigned int*)(xp16 + (size_t)s1 * 128 + 2 * lane);
        unsigned int u2 = *(const unsigned int*)(xp16 + (size_t)s2 * 128 + 2 * lane);
        unsigned int u3 = *(const unsigned int*)(xp16 + (size_t)s3 * 128 + 2 * lane);
        a0 += w0 * b2f_lo(u0) + w1 * b2f_lo(u1) + w2 * b2f_lo(u2) + w3 * b2f_lo(u3);
        a1 += w0 * b2f_hi(u0) + w1 * b2f_hi(u1) + w2 * b2f_hi(u2) + w3 * b2f_hi(u3);
    }
    for (; j < je; ++j) {
        int s = __builtin_amdgcn_readfirstlane(eidx[j]);
        float w = wp[(size_t)j * 4 + hh];
        unsigned int u = *(const unsigned int*)(xp16 + (size_t)s * 128 + 2 * lane);
        a0 += w * b2f_lo(u);
        a1 += w * b2f_hi(u);
    }
    float inv = ((const float*)(invden + d))[hh];
    float2 o = make_float2(a0 * inv + bias[2 * lane], a1 * inv + bias[2 * lane + 1]);
    *(float2*)(out + (size_t)d * 128 + 2 * lane) = o;
}

// ---------------- accumulation, layer 2: bf16 gather shared by 4 heads, unroll x4 ----------------
__global__ void k_accL2(const unsigned short* __restrict__ hb16, const float4* __restrict__ wp,
                        const float4* __restrict__ invden, const int* __restrict__ rowptr,
                        const int* __restrict__ eidx, unsigned short* __restrict__ agg16,
                        int N) {
    int d = (blockIdx.x * blockDim.x + threadIdx.x) >> 6;
    int lane = threadIdx.x & 63;
    if (d >= N) return;
    int jb = rowptr[d], je = rowptr[d + 1];
    float acc[4][2] = {{0.f, 0.f}, {0.f, 0.f}, {0.f, 0.f}, {0.f, 0.f}};
    int j = jb;
    for (; j + 4 <= je; j += 4) {
        int s0 = __builtin_amdgcn_readfirstlane(eidx[j]);
        int s1 = __builtin_amdgcn_readfirstlane(eidx[j + 1]);
        int s2 = __builtin_amdgcn_readfirstlane(eidx[j + 2]);
        int s3 = __builtin_amdgcn_readfirstlane(eidx[j + 3]);
        float4 w0 = wp[j], w1 = wp[j + 1], w2 = wp[j + 2], w3 = wp[j + 3];
        unsigned int u0 = *(const unsigned int*)(hb16 + (size_t)s0 * 128 + 2 * lane);
        unsigned int u1 = *(const unsigned int*)(hb16 + (size_t)s1 * 128 + 2 * lane);
        unsigned int u2 = *(const unsigned int*)(hb16 + (size_t)s2 * 128 + 2 * lane);
        unsigned int u3 = *(const unsigned int*)(hb16 + (size_t)s3 * 128 + 2 * lane);
        float lo0 = b2f_lo(u0), hi0 = b2f_hi(u0);
        float lo1 = b2f_lo(u1), hi1 = b2f_hi(u1);
        float lo2 = b2f_lo(u2), hi2 = b2f_hi(u2);
        float lo3 = b2f_lo(u3), hi3 = b2f_hi(u3);
#pragma unroll
        for (int hh = 0; hh < 4; hh++) {
            acc[hh][0] += ((const float*)&w0)[hh] * lo0 + ((const float*)&w1)[hh] * lo1 +
                          ((const float*)&w2)[hh] * lo2 + ((const float*)&w3)[hh] * lo3;
            acc[hh][1] += ((const float*)&w0)[hh] * hi0 + ((const float*)&w1)[hh] * hi1 +
                          ((const float*)&w2)[hh] * hi2 + ((const float*)&w3)[hh] * hi3;
        }
    }
    for (; j < je; ++j) {
        int s = __builtin_amdgcn_readfirstlane(eidx[j]);
        float4 w = wp[j];
        unsigned int u = *(const unsigned int*)(hb16 + (size_t)s * 128 + 2 * lane);
        float lo = b2f_lo(u), hi = b2f_hi(u);
#pragma unroll
        for (int hh = 0; hh < 4; hh++) {
            acc[hh][0] += ((const float*)&w)[hh] * lo;
            acc[hh][1] += ((const float*)&w)[hh] * hi;
        }
    }
    float4 inv = invden[d];
#pragma unroll
    for (int hh = 0; hh < 4; hh++) {
        float iv = ((const float*)&inv)[hh];
        ushort2 o = make_ushort2(f2b(acc[hh][0] * iv), f2b(acc[hh][1] * iv));
        *(ushort2*)(agg16 + (size_t)d * 512 + hh * 128 + 2 * lane) = o;
    }
}

// ---------------- batch norm ----------------
__global__ void k_bnstats(const float* __restrict__ x, float* __restrict__ sums, int N) {
    int col = threadIdx.x & 127, half = threadIdx.x >> 7;
    float s1 = 0.f, s2 = 0.f;
    for (int r = blockIdx.x * 2 + half; r < N; r += gridDim.x * 2) {
        float v = x[(size_t)r * 128 + col];
        s1 += v;
        s2 += v * v;
    }
    atomicAdd(&sums[col], s1);
    atomicAdd(&sums[128 + col], s2);
}

// normalize (+ELU) in place; optionally also emit bf16 copy for the next GEMM
__global__ void k_bnapply(float* __restrict__ x, unsigned short* __restrict__ out16,
                          const float* __restrict__ sums, const float* __restrict__ gamma,
                          const float* __restrict__ beta, int N, int elu) {
    int idx = blockIdx.x * blockDim.x + threadIdx.x;  // float4 index
    if (idx >= N * 32) return;
    float4 v = ((float4*)x)[idx];
    int colb = (idx & 31) * 4;
    float invN = 1.f / (float)N;
#pragma unroll
    for (int j = 0; j < 4; j++) {
        int col = colb + j;
        float mu = sums[col] * invN;
        float var = sums[128 + col] * invN - mu * mu;
        float y = (((float*)&v)[j] - mu) * rsqrtf(var + EPS_BN) * gamma[col] + beta[col];
        if (elu) y = y > 0.f ? y : __expf(y) - 1.f;
        ((float*)&v)[j] = y;
    }
    ((float4*)x)[idx] = v;
    if (out16) {
        ushort4 o = make_ushort4(f2b(v.x), f2b(v.y), f2b(v.z), f2b(v.w));
        ((ushort4*)out16)[idx] = o;
    }
}

// ---------------- launch ----------------
extern "C" void kernel_launch(void* const* d_in, const int* in_sizes, int n_in,
                              void* d_out, int out_size, void* d_ws, size_t ws_size,
                              hipStream_t stream) {
    const float* x = (const float*)d_in[0];
    const int* ei_raw = (const int*)d_in[1];
    const float* W0 = (const float*)d_in[2];
    const float* as0 = (const float*)d_in[3];
    const float* ad0 = (const float*)d_in[4];
    const float* b0 = (const float*)d_in[5];
    const float* g0 = (const float*)d_in[6];
    const float* be0 = (const float*)d_in[7];
    const float* W1 = (const float*)d_in[8];
    const float* as1 = (const float*)d_in[9];
    const float* ad1 = (const float*)d_in[10];
    const float* b1 = (const float*)d_in[11];
    const float* g1 = (const float*)d_in[12];
    const float* be1 = (const float*)d_in[13];
    const float* W2 = (const float*)d_in[14];
    const float* as2 = (const float*)d_in[15];
    const float* ad2 = (const float*)d_in[16];
    const float* g2v = (const float*)d_in[18];
    const float* be2 = (const float*)d_in[19];

    const int N = in_sizes[0] / 128;
    const int E = in_sizes[1] / 2;

    // workspace carve (256B aligned)
    char* p = (char*)d_ws;
    auto alloc = [&](size_t bytes) {
        void* r = (void*)p;
        p += (bytes + 255) & ~(size_t)255;
        return r;
    };
    float* xp = (float*)alloc((size_t)N * 128 * 4);      // per-layer projected features (fp32)
    float* hbuf = (float*)alloc((size_t)N * 128 * 4);    // hidden (fp32)
    unsigned short* xb = (unsigned short*)alloc((size_t)N * 128 * 2);    // bf16 of x
    unsigned short* xp16 = (unsigned short*)alloc((size_t)N * 128 * 2);  // bf16 of xp (gather payload)
    unsigned short* hb16 = (unsigned short*)alloc((size_t)N * 128 * 2);  // bf16 of hbuf
    unsigned short* agg16 = (unsigned short*)alloc((size_t)N * 512 * 2); // bf16 layer-2 aggregate
    float* As = (float*)alloc((size_t)N * 4 * 4);
    float* Ad = (float*)alloc((size_t)N * 4 * 4);
    int* deg = (int*)alloc((size_t)N * 4);
    int* rowptr = (int*)alloc((size_t)(N + 1) * 4);
    int* cursor = (int*)alloc((size_t)N * 4);
    int* bsum = (int*)alloc(1024);
    int* eidx = (int*)alloc((size_t)(E + N) * 4);
    float* bns = (float*)alloc(256 * 4);
    // union: ei32 (2E ints, CSR build only) then wp ((E+N) float4)
    size_t uni_bytes = (size_t)(E + N) * 16;
    size_t ei_bytes = (size_t)2 * E * 4;
    char* uni = (char*)alloc(uni_bytes > ei_bytes ? uni_bytes : ei_bytes);
    int* ei32 = (int*)uni;
    float4* wp = (float4*)uni;
    float4* invden = (float4*)alloc((size_t)N * 16);
    int* flag = (int*)alloc(256);
    float* Wt = (float*)alloc(1024 * 4);
    unsigned short* WT0 = (unsigned short*)alloc((size_t)128 * 128 * 2);
    unsigned short* WT1 = (unsigned short*)alloc((size_t)128 * 128 * 2);
    unsigned short* WT2 = (unsigned short*)alloc((size_t)128 * 512 * 2);
    if ((size_t)(p - (char*)d_ws) > ws_size) return;

    const int nb = (N + 255) / 256;
    const int gw = (N + 3) / 4;              // wave-per-node kernels
    const int gm = (N / 16 + 3) / 4 + 1;     // mgemm: wave per 16 rows

    // --- edge dtype normalize ---
    k_detect64<<<1, 64, 0, stream>>>(ei_raw, flag, 2 * E);
    k_convert<<<(2 * E + 255) / 256, 256, 0, stream>>>(ei_raw, flag, ei32, 2 * E);
    const int* srcv = ei32;
    const int* dstv = ei32 + E;

    // --- CSR build ---
    hipMemsetAsync(deg, 0, (size_t)N * 4, stream);
    k_deg_count<<<(E + 255) / 256, 256, 0, stream>>>(dstv, deg, E);
    k_scan1<<<nb, 256, 0, stream>>>(deg, rowptr, bsum, N);
    k_scan2<<<1, 256, 0, stream>>>(bsum, nb);
    k_scan3<<<nb, 256, 0, stream>>>(rowptr, bsum, N);
    k_cursor<<<nb, 256, 0, stream>>>(rowptr, cursor, N);
    k_scatter<<<(E + N + 255) / 256, 256, 0, stream>>>(srcv, dstv, cursor, eidx, E, N);

    // --- weight prep (bf16 transposed) + input cast ---
    k_wcvt<<<(128 * 128 + 255) / 256, 256, 0, stream>>>(W0, WT0, 128, 128);
    k_wcvt<<<(128 * 128 + 255) / 256, 256, 0, stream>>>(W1, WT1, 128, 128);
    k_w2cvt<<<(128 * 512 + 255) / 256, 256, 0, stream>>>(W2, WT2);
    k_makeWt<<<256, 256, 0, stream>>>(W2, as2, ad2, Wt);
    k_f2b4<<<(N * 32 + 255) / 256, 256, 0, stream>>>(x, xb, N * 32);

    // --- layer 0 ---
    k_mgemm<128><<<gm, 256, 0, stream>>>(xb, WT0, xp, xp16, N);
    k_att32<<<gw, 256, 0, stream>>>(xp, as0, ad0, As, Ad, N);
    k_edgew<<<gw, 256, 0, stream>>>(As, Ad, rowptr, eidx, wp, invden, N);
    k_acc01<<<gw, 256, 0, stream>>>(xp16, (const float*)wp, invden, rowptr, eidx, b0, hbuf, N);
    hipMemsetAsync(bns, 0, 256 * 4, stream);
    k_bnstats<<<256, 256, 0, stream>>>(hbuf, bns, N);
    k_bnapply<<<(N * 32 + 255) / 256, 256, 0, stream>>>(hbuf, hb16, bns, g0, be0, N, 1);

    // --- layer 1 ---
    k_mgemm<128><<<gm, 256, 0, stream>>>(hb16, WT1, xp, xp16, N);
    k_att32<<<gw, 256, 0, stream>>>(xp, as1, ad1, As, Ad, N);
    k_edgew<<<gw, 256, 0, stream>>>(As, Ad, rowptr, eidx, wp, invden, N);
    k_acc01<<<gw, 256, 0, stream>>>(xp16, (const float*)wp, invden, rowptr, eidx, b1, hbuf, N);
    hipMemsetAsync(bns, 0, 256 * 4, stream);
    k_bnstats<<<256, 256, 0, stream>>>(hbuf, bns, N);
    k_bnapply<<<(N * 32 + 255) / 256, 256, 0, stream>>>(hbuf, hb16, bns, g1, be1, N, 1);

    // --- layer 2 (linearity: aggregate h per head, then [N,512]@[512,128] MFMA GEMM) ---
    float* outf = (float*)d_out;
    k_attW<<<gw, 256, 0, stream>>>(hbuf, Wt, As, Ad, N);
    k_edgew<<<gw, 256, 0, stream>>>(As, Ad, rowptr, eidx, wp, invden, N);
    k_accL2<<<gw, 256, 0, stream>>>(hb16, wp, invden, rowptr, eidx, agg16, N);
    k_mgemm<512><<<gm, 256, 0, stream>>>(agg16, WT2, outf, (unsigned short*)nullptr, N);
    hipMemsetAsync(bns, 0, 256 * 4, stream);
    k_bnstats<<<256, 256, 0, stream>>>(outf, bns, N);
    k_bnapply<<<(N * 32 + 255) / 256, 256, 0, stream>>>(outf, (unsigned short*)nullptr, bns, g2v, be2, N, 0);
}

// Round 7
// 690.140 us; speedup vs baseline: 1.3947x; 1.0930x over previous
//
#include <hip/hip_runtime.h>
#include <math.h>

#define EPS_BN 1e-5f

typedef __bf16 bf16x8 __attribute__((ext_vector_type(8)));
typedef float floatx4 __attribute__((ext_vector_type(4)));

__device__ __forceinline__ float lrelu(float x) { return x > 0.f ? x : 0.2f * x; }

// fp32 -> bf16 (RNE) bit pattern
__device__ __forceinline__ unsigned short f2b(float f) {
    unsigned int b = __float_as_uint(f);
    b = (b + 0x7fffu + ((b >> 16) & 1u)) >> 16;
    return (unsigned short)b;
}
// packed ushort2(bf16x2) -> two floats
__device__ __forceinline__ float b2f_lo(unsigned int u) { return __uint_as_float(u << 16); }
__device__ __forceinline__ float b2f_hi(unsigned int u) { return __uint_as_float(u & 0xffff0000u); }

// ---------------- edge dtype probe (parallel) + convert ----------------
__global__ void k_detect64(const int* __restrict__ ei, int* flag, int nwords) {
    int lane = threadIdx.x;  // 64
    int lim = nwords < 512 ? nwords : 512;
    int zeros = 0;
    for (int i = 2 * lane + 1; i < lim; i += 128) zeros += (ei[i] == 0);
    for (int off = 32; off >= 1; off >>= 1) zeros += __shfl_xor(zeros, off, 64);
    if (lane == 0) *flag = (zeros > lim / 8) ? 1 : 0;
}

__global__ void k_convert(const int* __restrict__ ei, const int* __restrict__ flag,
                          int* __restrict__ out, int n) {
    int i = blockIdx.x * blockDim.x + threadIdx.x;
    int f = *flag;  // uniform
    if (i < n) out[i] = f ? ei[2 * i] : ei[i];
}

// ---------------- CSR build ----------------
__global__ void k_deg_count(const int* __restrict__ dst, int* deg, int E) {
    int i = blockIdx.x * blockDim.x + threadIdx.x;
    if (i < E) atomicAdd(&deg[dst[i]], 1);
}

// +1 inside scan accounts for the self loop (deg[] holds only real in-edges)
__global__ void k_scan1(const int* __restrict__ deg, int* rowptr, int* bsum, int N) {
    __shared__ int lds[256];
    int t = threadIdx.x, n = blockIdx.x * 256 + t;
    int v = (n < N) ? deg[n] + 1 : 0;
    int xv = v;
    lds[t] = xv;
    __syncthreads();
    for (int off = 1; off < 256; off <<= 1) {
        int tmp = (t >= off) ? lds[t - off] : 0;
        __syncthreads();
        xv += tmp;
        lds[t] = xv;
        __syncthreads();
    }
    if (n < N) rowptr[n + 1] = xv;
    if (t == 255) bsum[blockIdx.x] = xv;
}

__global__ void k_scan2(int* bsum, int nb) {
    __shared__ int lds[256];
    int t = threadIdx.x;
    int v = (t < nb) ? bsum[t] : 0;
    int xv = v;
    lds[t] = xv;
    __syncthreads();
    for (int off = 1; off < 256; off <<= 1) {
        int tmp = (t >= off) ? lds[t - off] : 0;
        __syncthreads();
        xv += tmp;
        lds[t] = xv;
        __syncthreads();
    }
    if (t < nb) bsum[t] = xv - v;  // exclusive
}

__global__ void k_scan3(int* rowptr, const int* __restrict__ bsum, int N) {
    int n = blockIdx.x * 256 + threadIdx.x;
    if (n < N) rowptr[n + 1] += bsum[blockIdx.x];
    if (n == 0) rowptr[0] = 0;
}

__global__ void k_cursor(const int* __restrict__ rowptr, int* cursor, int N) {
    int n = blockIdx.x * blockDim.x + threadIdx.x;
    if (n < N) cursor[n] = rowptr[n];
}

__global__ void k_scatter(const int* __restrict__ src, const int* __restrict__ dst,
                          int* cursor, int* eidx, int E, int N) {
    int i = blockIdx.x * blockDim.x + threadIdx.x;
    if (i < E) {
        int s = src[i], d = dst[i];
        int pos = atomicAdd(&cursor[d], 1);
        eidx[pos] = s;
    } else if (i < E + N) {
        int n_ = i - E;
        int pos = atomicAdd(&cursor[n_], 1);
        eidx[pos] = n_;  // self loop
    }
}

// ---------------- fp32 -> bf16 cast (4 elems/thread) ----------------
__global__ void k_f2b4(const float* __restrict__ in, unsigned short* __restrict__ out, int n4) {
    int i = blockIdx.x * blockDim.x + threadIdx.x;
    if (i >= n4) return;
    float4 v = ((const float4*)in)[i];
    ushort4 o = make_ushort4(f2b(v.x), f2b(v.y), f2b(v.z), f2b(v.w));
    ((ushort4*)out)[i] = o;
}

// ---------------- weight convert+transpose: WT[c][k] = W[k][c] ----------------
__global__ void k_wcvt(const float* __restrict__ W, unsigned short* __restrict__ WT,
                       int K, int M) {
    int idx = blockIdx.x * blockDim.x + threadIdx.x;
    if (idx >= K * M) return;
    int c = idx / K, k = idx - c * K;
    WT[idx] = f2b(W[(size_t)k * M + c]);
}

// W2 special: WT2[c][j] = 0.25*W2[(j&127)*512 + (j>>7)*128 + c]  (j = h*128+k; folds head-mean)
__global__ void k_w2cvt(const float* __restrict__ W2, unsigned short* __restrict__ WT2) {
    int idx = blockIdx.x * blockDim.x + threadIdx.x;
    if (idx >= 128 * 512) return;
    int c = idx >> 9, j = idx & 511;
    WT2[idx] = f2b(0.25f * W2[(size_t)(j & 127) * 512 + (j >> 7) * 128 + c]);
}

// ---------------- LDS fragment load: two 8B reads (stride-72B rows, align 8) ----------------
__device__ __forceinline__ bf16x8 lds_frag(const unsigned short* pp) {
    union { bf16x8 v; uint2 u2[2]; } t;
    t.u2[0] = *(const uint2*)pp;
    t.u2[1] = *(const uint2*)(pp + 4);
    return t.v;
}

// ---------------- tiled MFMA GEMM: out[N,128] = A16[N,K] @ W (via WT[128][K]) ----------------
// block = 256 threads (4 waves) -> 64 rows x 128 cols tile; BK=32; LDS-staged A and B
// with 72B row stride (4-way LDS bank aliasing, best available at 8B alignment).
// Prefetch next k-slice into registers before compute. Optional bf16 dual-write.
template <int K>
__global__ __launch_bounds__(256) void k_tgemm(const unsigned short* __restrict__ A,
                                               const unsigned short* __restrict__ WT,
                                               float* __restrict__ out,
                                               unsigned short* __restrict__ out16, int N) {
    __shared__ unsigned short Ast[64 * 36];   // [row][36] (72 B stride)
    __shared__ unsigned short Bst[128 * 36];  // [col][36]
    const int tid = threadIdx.x;
    const int lane = tid & 63, w = tid >> 6;
    const int l16 = lane & 15, quad = lane >> 4;
    const int rowbase = blockIdx.x * 64;
    // staging: A -> thread t covers (row t/4, 16B chunk t%4); B -> (col t/2, chunks t%2 and t%2+2)
    const int sar = tid >> 2, sak = tid & 3;
    const int sbc = tid >> 1, sbk = tid & 1;
    const long arow_g = min(rowbase + sar, N - 1);

    floatx4 acc[8];
#pragma unroll
    for (int c = 0; c < 8; c++) acc[c] = (floatx4){0.f, 0.f, 0.f, 0.f};

    uint4 rA, rB0, rB1;
    const unsigned short* Ag = A + (size_t)arow_g * K + sak * 8;
    const unsigned short* Bg = WT + (size_t)sbc * K + sbk * 8;
    rA = *(const uint4*)(Ag);
    rB0 = *(const uint4*)(Bg);
    rB1 = *(const uint4*)(Bg + 16);

    unsigned short* Aw = Ast + sar * 36 + sak * 8;
    unsigned short* Bw0 = Bst + sbc * 36 + sbk * 8;
    unsigned short* Bw1 = Bw0 + 16;
    const unsigned short* Ar = Ast + (w * 16 + l16) * 36 + quad * 8;
    const unsigned short* Br = Bst + l16 * 36 + quad * 8;

#pragma unroll
    for (int k0 = 0; k0 < K; k0 += 32) {
        __syncthreads();  // previous compute done before overwriting LDS
        *(uint2*)(Aw) = make_uint2(rA.x, rA.y);
        *(uint2*)(Aw + 4) = make_uint2(rA.z, rA.w);
        *(uint2*)(Bw0) = make_uint2(rB0.x, rB0.y);
        *(uint2*)(Bw0 + 4) = make_uint2(rB0.z, rB0.w);
        *(uint2*)(Bw1) = make_uint2(rB1.x, rB1.y);
        *(uint2*)(Bw1 + 4) = make_uint2(rB1.z, rB1.w);
        __syncthreads();
        if (k0 + 32 < K) {  // prefetch next slice while computing this one
            rA = *(const uint4*)(Ag + k0 + 32);
            rB0 = *(const uint4*)(Bg + k0 + 32);
            rB1 = *(const uint4*)(Bg + k0 + 48);
        }
        bf16x8 af = lds_frag(Ar);
#pragma unroll
        for (int c = 0; c < 8; c++) {
            bf16x8 bf = lds_frag(Br + c * 16 * 36);
            acc[c] = __builtin_amdgcn_mfma_f32_16x16x32_bf16(af, bf, acc[c], 0, 0, 0);
        }
    }

    const int row00 = rowbase + w * 16 + quad * 4;
#pragma unroll
    for (int c = 0; c < 8; c++) {
#pragma unroll
        for (int r = 0; r < 4; r++) {
            int row = row00 + r;
            if (row < N) {
                out[(size_t)row * 128 + c * 16 + l16] = acc[c][r];
                if (out16) out16[(size_t)row * 128 + c * 16 + l16] = f2b(acc[c][r]);
            }
        }
    }
}

// ---------------- attention scores, layers 0/1 ----------------
__global__ void k_att32(const float* __restrict__ xp, const float* __restrict__ att_s,
                        const float* __restrict__ att_d, float* __restrict__ a_s,
                        float* __restrict__ a_d, int N) {
    int wid = (blockIdx.x * blockDim.x + threadIdx.x) >> 6;
    int lane = threadIdx.x & 63;
    if (wid >= N) return;
    const float* xr = xp + (size_t)wid * 128;
    float x0 = xr[lane], x1 = xr[lane + 64];
    float ps0 = x0 * att_s[lane], ps1 = x1 * att_s[lane + 64];
    float pd0 = x0 * att_d[lane], pd1 = x1 * att_d[lane + 64];
    for (int m = 16; m >= 1; m >>= 1) {
        ps0 += __shfl_xor(ps0, m, 64);
        ps1 += __shfl_xor(ps1, m, 64);
        pd0 += __shfl_xor(pd0, m, 64);
        pd1 += __shfl_xor(pd1, m, 64);
    }
    if ((lane & 31) == 0) {
        int h = lane >> 5;
        a_s[wid * 4 + h] = ps0;
        a_s[wid * 4 + 2 + h] = ps1;
        a_d[wid * 4 + h] = pd0;
        a_d[wid * 4 + 2 + h] = pd1;
    }
}

// ---------------- layer 2 score precompute ----------------
__global__ void k_makeWt(const float* __restrict__ W2, const float* __restrict__ as2,
                         const float* __restrict__ ad2, float* __restrict__ Wt) {
    int wid = (blockIdx.x * blockDim.x + threadIdx.x) >> 6;
    int lane = threadIdx.x & 63;
    if (wid >= 1024) return;
    int k = wid & 127, hh = (wid >> 7) & 3, isd = wid >> 9;
    const float* att = isd ? ad2 : as2;
    float v = W2[(size_t)k * 512 + hh * 128 + lane] * att[hh * 128 + lane] +
              W2[(size_t)k * 512 + hh * 128 + 64 + lane] * att[hh * 128 + 64 + lane];
    for (int m = 32; m >= 1; m >>= 1) v += __shfl_xor(v, m, 64);
    if (lane == 0) Wt[isd * 512 + hh * 128 + k] = v;
}

// ---------------- layer 2 scores from h ----------------
__global__ void k_attW(const float* __restrict__ hb, const float* __restrict__ Wt,
                       float* __restrict__ a_s, float* __restrict__ a_d, int N) {
    int wid = (blockIdx.x * blockDim.x + threadIdx.x) >> 6;
    int lane = threadIdx.x & 63;
    if (wid >= N) return;
    float x0 = hb[(size_t)wid * 128 + lane], x1 = hb[(size_t)wid * 128 + 64 + lane];
    float ts[4], td[4];
#pragma unroll
    for (int hh = 0; hh < 4; hh++) {
        ts[hh] = x0 * Wt[hh * 128 + lane] + x1 * Wt[hh * 128 + 64 + lane];
        td[hh] = x0 * Wt[512 + hh * 128 + lane] + x1 * Wt[512 + hh * 128 + 64 + lane];
    }
    for (int m = 32; m >= 1; m >>= 1) {
#pragma unroll
        for (int hh = 0; hh < 4; hh++) {
            ts[hh] += __shfl_xor(ts[hh], m, 64);
            td[hh] += __shfl_xor(td[hh], m, 64);
        }
    }
    if (lane == 0) {
#pragma unroll
        for (int hh = 0; hh < 4; hh++) {
            a_s[wid * 4 + hh] = ts[hh];
            a_d[wid * 4 + hh] = td[hh];
        }
    }
}

// ---------------- edge softmax weights ----------------
__global__ void k_edgew(const float* __restrict__ a_s, const float* __restrict__ a_d,
                        const int* __restrict__ rowptr, const int* __restrict__ eidx,
                        float4* __restrict__ wp, float4* __restrict__ invden, int N) {
    int d = (blockIdx.x * blockDim.x + threadIdx.x) >> 6;
    int lane = threadIdx.x & 63;
    if (d >= N) return;
    float4 ad4 = *(const float4*)(a_d + (size_t)d * 4);
    int jb = rowptr[d], je = rowptr[d + 1], deg = je - jb;
    int j = jb + lane;
    if (deg <= 64) {
        float e[4] = {-INFINITY, -INFINITY, -INFINITY, -INFINITY};
        if (j < je) {
            int s = eidx[j];
            float4 as4 = *(const float4*)(a_s + (size_t)s * 4);
#pragma unroll
            for (int hh = 0; hh < 4; hh++)
                e[hh] = lrelu(((const float*)&as4)[hh] + ((const float*)&ad4)[hh]);
        }
        float m[4] = {e[0], e[1], e[2], e[3]};
        for (int off = 32; off >= 1; off >>= 1) {
#pragma unroll
            for (int hh = 0; hh < 4; hh++) m[hh] = fmaxf(m[hh], __shfl_xor(m[hh], off, 64));
        }
        float p[4], den[4];
#pragma unroll
        for (int hh = 0; hh < 4; hh++) {
            p[hh] = (j < je) ? __expf(e[hh] - m[hh]) : 0.f;
            den[hh] = p[hh];
        }
        for (int off = 32; off >= 1; off >>= 1) {
#pragma unroll
            for (int hh = 0; hh < 4; hh++) den[hh] += __shfl_xor(den[hh], off, 64);
        }
        if (j < je) wp[j] = make_float4(p[0], p[1], p[2], p[3]);
        if (lane == 0)
            invden[d] = make_float4(1.f / (den[0] + 1e-16f), 1.f / (den[1] + 1e-16f),
                                    1.f / (den[2] + 1e-16f), 1.f / (den[3] + 1e-16f));
    } else {
        float m[4] = {-INFINITY, -INFINITY, -INFINITY, -INFINITY};
        for (int jj = j; jj < je; jj += 64) {
            int s = eidx[jj];
            float4 as4 = *(const float4*)(a_s + (size_t)s * 4);
#pragma unroll
            for (int hh = 0; hh < 4; hh++)
                m[hh] = fmaxf(m[hh], lrelu(((const float*)&as4)[hh] + ((const float*)&ad4)[hh]));
        }
        for (int off = 32; off >= 1; off >>= 1) {
#pragma unroll
            for (int hh = 0; hh < 4; hh++) m[hh] = fmaxf(m[hh], __shfl_xor(m[hh], off, 64));
        }
        float den[4] = {0.f, 0.f, 0.f, 0.f};
        for (int jj = j; jj < je; jj += 64) {
            int s = eidx[jj];
            float4 as4 = *(const float4*)(a_s + (size_t)s * 4);
            float p[4];
#pragma unroll
            for (int hh = 0; hh < 4; hh++) {
                float e = lrelu(((const float*)&as4)[hh] + ((const float*)&ad4)[hh]);
                p[hh] = __expf(e - m[hh]);
                den[hh] += p[hh];
            }
            wp[jj] = make_float4(p[0], p[1], p[2], p[3]);
        }
        for (int off = 32; off >= 1; off >>= 1) {
#pragma unroll
            for (int hh = 0; hh < 4; hh++) den[hh] += __shfl_xor(den[hh], off, 64);
        }
        if (lane == 0)
            invden[d] = make_float4(1.f / (den[0] + 1e-16f), 1.f / (den[1] + 1e-16f),
                                    1.f / (den[2] + 1e-16f), 1.f / (den[3] + 1e-16f));
    }
}

// ---------------- accumulation, layers 0/1: bf16 gather, unroll x4 for MLP ----------------
__global__ void k_acc01(const unsigned short* __restrict__ xp16, const float* __restrict__ wp,
                        const float4* __restrict__ invden, const int* __restrict__ rowptr,
                        const int* __restrict__ eidx, const float* __restrict__ bias,
                        float* __restrict__ out, int N) {
    int d = (blockIdx.x * blockDim.x + threadIdx.x) >> 6;
    int lane = threadIdx.x & 63;
    if (d >= N) return;
    int hh = lane >> 4;
    int jb = rowptr[d], je = rowptr[d + 1];
    float a0 = 0.f, a1 = 0.f;
    int j = jb;
    for (; j + 4 <= je; j += 4) {
        int s0 = __builtin_amdgcn_readfirstlane(eidx[j]);
        int s1 = __builtin_amdgcn_readfirstlane(eidx[j + 1]);
        int s2 = __builtin_amdgcn_readfirstlane(eidx[j + 2]);
        int s3 = __builtin_amdgcn_readfirstlane(eidx[j + 3]);
        float w0 = wp[(size_t)j * 4 + hh];
        float w1 = wp[(size_t)(j + 1) * 4 + hh];
        float w2 = wp[(size_t)(j + 2) * 4 + hh];
        float w3 = wp[(size_t)(j + 3) * 4 + hh];
        unsigned int u0 = *(const unsigned int*)(xp16 + (size_t)s0 * 128 + 2 * lane);
        unsigned int u1 = *(const unsigned int*)(xp16 + (size_t)s1 * 128 + 2 * lane);
        unsigned int u2 = *(const unsigned int*)(xp16 + (size_t)s2 * 128 + 2 * lane);
        unsigned int u3 = *(const unsigned int*)(xp16 + (size_t)s3 * 128 + 2 * lane);
        a0 += w0 * b2f_lo(u0) + w1 * b2f_lo(u1) + w2 * b2f_lo(u2) + w3 * b2f_lo(u3);
        a1 += w0 * b2f_hi(u0) + w1 * b2f_hi(u1) + w2 * b2f_hi(u2) + w3 * b2f_hi(u3);
    }
    for (; j < je; ++j) {
        int s = __builtin_amdgcn_readfirstlane(eidx[j]);
        float w = wp[(size_t)j * 4 + hh];
        unsigned int u = *(const unsigned int*)(xp16 + (size_t)s * 128 + 2 * lane);
        a0 += w * b2f_lo(u);
        a1 += w * b2f_hi(u);
    }
    float inv = ((const float*)(invden + d))[hh];
    float2 o = make_float2(a0 * inv + bias[2 * lane], a1 * inv + bias[2 * lane + 1]);
    *(float2*)(out + (size_t)d * 128 + 2 * lane) = o;
}

// ---------------- accumulation, layer 2: bf16 gather shared by 4 heads, unroll x4 ----------------
__global__ void k_accL2(const unsigned short* __restrict__ hb16, const float4* __restrict__ wp,
                        const float4* __restrict__ invden, const int* __restrict__ rowptr,
                        const int* __restrict__ eidx, unsigned short* __restrict__ agg16,
                        int N) {
    int d = (blockIdx.x * blockDim.x + threadIdx.x) >> 6;
    int lane = threadIdx.x & 63;
    if (d >= N) return;
    int jb = rowptr[d], je = rowptr[d + 1];
    float acc[4][2] = {{0.f, 0.f}, {0.f, 0.f}, {0.f, 0.f}, {0.f, 0.f}};
    int j = jb;
    for (; j + 4 <= je; j += 4) {
        int s0 = __builtin_amdgcn_readfirstlane(eidx[j]);
        int s1 = __builtin_amdgcn_readfirstlane(eidx[j + 1]);
        int s2 = __builtin_amdgcn_readfirstlane(eidx[j + 2]);
        int s3 = __builtin_amdgcn_readfirstlane(eidx[j + 3]);
        float4 w0 = wp[j], w1 = wp[j + 1], w2 = wp[j + 2], w3 = wp[j + 3];
        unsigned int u0 = *(const unsigned int*)(hb16 + (size_t)s0 * 128 + 2 * lane);
        unsigned int u1 = *(const unsigned int*)(hb16 + (size_t)s1 * 128 + 2 * lane);
        unsigned int u2 = *(const unsigned int*)(hb16 + (size_t)s2 * 128 + 2 * lane);
        unsigned int u3 = *(const unsigned int*)(hb16 + (size_t)s3 * 128 + 2 * lane);
        float lo0 = b2f_lo(u0), hi0 = b2f_hi(u0);
        float lo1 = b2f_lo(u1), hi1 = b2f_hi(u1);
        float lo2 = b2f_lo(u2), hi2 = b2f_hi(u2);
        float lo3 = b2f_lo(u3), hi3 = b2f_hi(u3);
#pragma unroll
        for (int hh = 0; hh < 4; hh++) {
            acc[hh][0] += ((const float*)&w0)[hh] * lo0 + ((const float*)&w1)[hh] * lo1 +
                          ((const float*)&w2)[hh] * lo2 + ((const float*)&w3)[hh] * lo3;
            acc[hh][1] += ((const float*)&w0)[hh] * hi0 + ((const float*)&w1)[hh] * hi1 +
                          ((const float*)&w2)[hh] * hi2 + ((const float*)&w3)[hh] * hi3;
        }
    }
    for (; j < je; ++j) {
        int s = __builtin_amdgcn_readfirstlane(eidx[j]);
        float4 w = wp[j];
        unsigned int u = *(const unsigned int*)(hb16 + (size_t)s * 128 + 2 * lane);
        float lo = b2f_lo(u), hi = b2f_hi(u);
#pragma unroll
        for (int hh = 0; hh < 4; hh++) {
            acc[hh][0] += ((const float*)&w)[hh] * lo;
            acc[hh][1] += ((const float*)&w)[hh] * hi;
        }
    }
    float4 inv = invden[d];
#pragma unroll
    for (int hh = 0; hh < 4; hh++) {
        float iv = ((const float*)&inv)[hh];
        ushort2 o = make_ushort2(f2b(acc[hh][0] * iv), f2b(acc[hh][1] * iv));
        *(ushort2*)(agg16 + (size_t)d * 512 + hh * 128 + 2 * lane) = o;
    }
}

// ---------------- batch norm ----------------
__global__ void k_bnstats(const float* __restrict__ x, float* __restrict__ sums, int N) {
    int col = threadIdx.x & 127, half = threadIdx.x >> 7;
    float s1 = 0.f, s2 = 0.f;
    for (int r = blockIdx.x * 2 + half; r < N; r += gridDim.x * 2) {
        float v = x[(size_t)r * 128 + col];
        s1 += v;
        s2 += v * v;
    }
    atomicAdd(&sums[col], s1);
    atomicAdd(&sums[128 + col], s2);
}

// normalize (+ELU) in place; optionally also emit bf16 copy for the next GEMM
__global__ void k_bnapply(float* __restrict__ x, unsigned short* __restrict__ out16,
                          const float* __restrict__ sums, const float* __restrict__ gamma,
                          const float* __restrict__ beta, int N, int elu) {
    int idx = blockIdx.x * blockDim.x + threadIdx.x;  // float4 index
    if (idx >= N * 32) return;
    float4 v = ((float4*)x)[idx];
    int colb = (idx & 31) * 4;
    float invN = 1.f / (float)N;
#pragma unroll
    for (int j = 0; j < 4; j++) {
        int col = colb + j;
        float mu = sums[col] * invN;
        float var = sums[128 + col] * invN - mu * mu;
        float y = (((float*)&v)[j] - mu) * rsqrtf(var + EPS_BN) * gamma[col] + beta[col];
        if (elu) y = y > 0.f ? y : __expf(y) - 1.f;
        ((float*)&v)[j] = y;
    }
    ((float4*)x)[idx] = v;
    if (out16) {
        ushort4 o = make_ushort4(f2b(v.x), f2b(v.y), f2b(v.z), f2b(v.w));
        ((ushort4*)out16)[idx] = o;
    }
}

// ---------------- launch ----------------
extern "C" void kernel_launch(void* const* d_in, const int* in_sizes, int n_in,
                              void* d_out, int out_size, void* d_ws, size_t ws_size,
                              hipStream_t stream) {
    const float* x = (const float*)d_in[0];
    const int* ei_raw = (const int*)d_in[1];
    const float* W0 = (const float*)d_in[2];
    const float* as0 = (const float*)d_in[3];
    const float* ad0 = (const float*)d_in[4];
    const float* b0 = (const float*)d_in[5];
    const float* g0 = (const float*)d_in[6];
    const float* be0 = (const float*)d_in[7];
    const float* W1 = (const float*)d_in[8];
    const float* as1 = (const float*)d_in[9];
    const float* ad1 = (const float*)d_in[10];
    const float* b1 = (const float*)d_in[11];
    const float* g1 = (const float*)d_in[12];
    const float* be1 = (const float*)d_in[13];
    const float* W2 = (const float*)d_in[14];
    const float* as2 = (const float*)d_in[15];
    const float* ad2 = (const float*)d_in[16];
    const float* g2v = (const float*)d_in[18];
    const float* be2 = (const float*)d_in[19];

    const int N = in_sizes[0] / 128;
    const int E = in_sizes[1] / 2;

    // workspace carve (256B aligned)
    char* p = (char*)d_ws;
    auto alloc = [&](size_t bytes) {
        void* r = (void*)p;
        p += (bytes + 255) & ~(size_t)255;
        return r;
    };
    float* xp = (float*)alloc((size_t)N * 128 * 4);      // per-layer projected features (fp32)
    float* hbuf = (float*)alloc((size_t)N * 128 * 4);    // hidden (fp32)
    unsigned short* xb = (unsigned short*)alloc((size_t)N * 128 * 2);    // bf16 of x
    unsigned short* xp16 = (unsigned short*)alloc((size_t)N * 128 * 2);  // bf16 of xp (gather payload)
    unsigned short* hb16 = (unsigned short*)alloc((size_t)N * 128 * 2);  // bf16 of hbuf
    unsigned short* agg16 = (unsigned short*)alloc((size_t)N * 512 * 2); // bf16 layer-2 aggregate
    float* As = (float*)alloc((size_t)N * 4 * 4);
    float* Ad = (float*)alloc((size_t)N * 4 * 4);
    int* deg = (int*)alloc((size_t)N * 4);
    int* rowptr = (int*)alloc((size_t)(N + 1) * 4);
    int* cursor = (int*)alloc((size_t)N * 4);
    int* bsum = (int*)alloc(1024);
    int* eidx = (int*)alloc((size_t)(E + N) * 4);
    float* bns = (float*)alloc(256 * 4);
    // union: ei32 (2E ints, CSR build only) then wp ((E+N) float4)
    size_t uni_bytes = (size_t)(E + N) * 16;
    size_t ei_bytes = (size_t)2 * E * 4;
    char* uni = (char*)alloc(uni_bytes > ei_bytes ? uni_bytes : ei_bytes);
    int* ei32 = (int*)uni;
    float4* wp = (float4*)uni;
    float4* invden = (float4*)alloc((size_t)N * 16);
    int* flag = (int*)alloc(256);
    float* Wt = (float*)alloc(1024 * 4);
    unsigned short* WT0 = (unsigned short*)alloc((size_t)128 * 128 * 2);
    unsigned short* WT1 = (unsigned short*)alloc((size_t)128 * 128 * 2);
    unsigned short* WT2 = (unsigned short*)alloc((size_t)128 * 512 * 2);
    if ((size_t)(p - (char*)d_ws) > ws_size) return;

    const int nb = (N + 255) / 256;
    const int gw = (N + 3) / 4;              // wave-per-node kernels
    const int gt = (N + 63) / 64;            // tiled GEMM: 64 rows per block

    // --- edge dtype normalize ---
    k_detect64<<<1, 64, 0, stream>>>(ei_raw, flag, 2 * E);
    k_convert<<<(2 * E + 255) / 256, 256, 0, stream>>>(ei_raw, flag, ei32, 2 * E);
    const int* srcv = ei32;
    const int* dstv = ei32 + E;

    // --- CSR build ---
    hipMemsetAsync(deg, 0, (size_t)N * 4, stream);
    k_deg_count<<<(E + 255) / 256, 256, 0, stream>>>(dstv, deg, E);
    k_scan1<<<nb, 256, 0, stream>>>(deg, rowptr, bsum, N);
    k_scan2<<<1, 256, 0, stream>>>(bsum, nb);
    k_scan3<<<nb, 256, 0, stream>>>(rowptr, bsum, N);
    k_cursor<<<nb, 256, 0, stream>>>(rowptr, cursor, N);
    k_scatter<<<(E + N + 255) / 256, 256, 0, stream>>>(srcv, dstv, cursor, eidx, E, N);

    // --- weight prep (bf16 transposed) + input cast ---
    k_wcvt<<<(128 * 128 + 255) / 256, 256, 0, stream>>>(W0, WT0, 128, 128);
    k_wcvt<<<(128 * 128 + 255) / 256, 256, 0, stream>>>(W1, WT1, 128, 128);
    k_w2cvt<<<(128 * 512 + 255) / 256, 256, 0, stream>>>(W2, WT2);
    k_makeWt<<<256, 256, 0, stream>>>(W2, as2, ad2, Wt);
    k_f2b4<<<(N * 32 + 255) / 256, 256, 0, stream>>>(x, xb, N * 32);

    // --- layer 0 ---
    k_tgemm<128><<<gt, 256, 0, stream>>>(xb, WT0, xp, xp16, N);
    k_att32<<<gw, 256, 0, stream>>>(xp, as0, ad0, As, Ad, N);
    k_edgew<<<gw, 256, 0, stream>>>(As, Ad, rowptr, eidx, wp, invden, N);
    k_acc01<<<gw, 256, 0, stream>>>(xp16, (const float*)wp, invden, rowptr, eidx, b0, hbuf, N);
    hipMemsetAsync(bns, 0, 256 * 4, stream);
    k_bnstats<<<256, 256, 0, stream>>>(hbuf, bns, N);
    k_bnapply<<<(N * 32 + 255) / 256, 256, 0, stream>>>(hbuf, hb16, bns, g0, be0, N, 1);

    // --- layer 1 ---
    k_tgemm<128><<<gt, 256, 0, stream>>>(hb16, WT1, xp, xp16, N);
    k_att32<<<gw, 256, 0, stream>>>(xp, as1, ad1, As, Ad, N);
    k_edgew<<<gw, 256, 0, stream>>>(As, Ad, rowptr, eidx, wp, invden, N);
    k_acc01<<<gw, 256, 0, stream>>>(xp16, (const float*)wp, invden, rowptr, eidx, b1, hbuf, N);
    hipMemsetAsync(bns, 0, 256 * 4, stream);
    k_bnstats<<<256, 256, 0, stream>>>(hbuf, bns, N);
    k_bnapply<<<(N * 32 + 255) / 256, 256, 0, stream>>>(hbuf, hb16, bns, g1, be1, N, 1);

    // --- layer 2 (linearity: aggregate h per head, then [N,512]@[512,128] MFMA GEMM) ---
    float* outf = (float*)d_out;
    k_attW<<<gw, 256, 0, stream>>>(hbuf, Wt, As, Ad, N);
    k_edgew<<<gw, 256, 0, stream>>>(As, Ad, rowptr, eidx, wp, invden, N);
    k_accL2<<<gw, 256, 0, stream>>>(hb16, wp, invden, rowptr, eidx, agg16, N);
    k_tgemm<512><<<gt, 256, 0, stream>>>(agg16, WT2, outf, (unsigned short*)nullptr, N);
    hipMemsetAsync(bns, 0, 256 * 4, stream);
    k_bnstats<<<256, 256, 0, stream>>>(outf, bns, N);
    k_bnapply<<<(N * 32 + 255) / 256, 256, 0, stream>>>(outf, (unsigned short*)nullptr, bns, g2v, be2, N, 0);
}

// Round 8
// 678.120 us; speedup vs baseline: 1.4194x; 1.0177x over previous
//
#include <hip/hip_runtime.h>
#include <math.h>

#define EPS_BN 1e-5f

typedef __bf16 bf16x8 __attribute__((ext_vector_type(8)));
typedef float floatx4 __attribute__((ext_vector_type(4)));

__device__ __forceinline__ float lrelu(float x) { return x > 0.f ? x : 0.2f * x; }

// fp32 -> bf16 (RNE) bit pattern
__device__ __forceinline__ unsigned short f2b(float f) {
    unsigned int b = __float_as_uint(f);
    b = (b + 0x7fffu + ((b >> 16) & 1u)) >> 16;
    return (unsigned short)b;
}
// packed ushort2(bf16x2) -> two floats
__device__ __forceinline__ float b2f_lo(unsigned int u) { return __uint_as_float(u << 16); }
__device__ __forceinline__ float b2f_hi(unsigned int u) { return __uint_as_float(u & 0xffff0000u); }

// ---------------- edge dtype probe (parallel) + convert ----------------
__global__ void k_detect64(const int* __restrict__ ei, int* flag, int nwords) {
    int lane = threadIdx.x;  // 64
    int lim = nwords < 512 ? nwords : 512;
    int zeros = 0;
    for (int i = 2 * lane + 1; i < lim; i += 128) zeros += (ei[i] == 0);
    for (int off = 32; off >= 1; off >>= 1) zeros += __shfl_xor(zeros, off, 64);
    if (lane == 0) *flag = (zeros > lim / 8) ? 1 : 0;
}

// 4 outputs per thread (independent loads in flight)
__global__ void k_convert(const int* __restrict__ ei, const int* __restrict__ flag,
                          int* __restrict__ out, int n) {
    int i0 = (blockIdx.x * blockDim.x + threadIdx.x) * 4;
    int f = *flag;  // uniform
    if (i0 + 4 <= n) {
        int v0, v1, v2, v3;
        if (f) {
            v0 = ei[2 * i0];
            v1 = ei[2 * i0 + 2];
            v2 = ei[2 * i0 + 4];
            v3 = ei[2 * i0 + 6];
        } else {
            int4 v = *(const int4*)(ei + i0);
            v0 = v.x; v1 = v.y; v2 = v.z; v3 = v.w;
        }
        *(int4*)(out + i0) = make_int4(v0, v1, v2, v3);
    } else {
        for (int i = i0; i < n; ++i) out[i] = f ? ei[2 * i] : ei[i];
    }
}

// ---------------- CSR build ----------------
// 4 edges per thread: 4 independent atomics in flight
__global__ void k_deg_count(const int* __restrict__ dst, int* deg, int E) {
    int i0 = (blockIdx.x * blockDim.x + threadIdx.x) * 4;
    if (i0 + 4 <= E) {
        int4 d = *(const int4*)(dst + i0);
        atomicAdd(&deg[d.x], 1);
        atomicAdd(&deg[d.y], 1);
        atomicAdd(&deg[d.z], 1);
        atomicAdd(&deg[d.w], 1);
    } else {
        for (int i = i0; i < E; ++i) atomicAdd(&deg[dst[i]], 1);
    }
}

// +1 inside scan accounts for the self loop (deg[] holds only real in-edges)
__global__ void k_scan1(const int* __restrict__ deg, int* rowptr, int* bsum, int N) {
    __shared__ int lds[256];
    int t = threadIdx.x, n = blockIdx.x * 256 + t;
    int v = (n < N) ? deg[n] + 1 : 0;
    int xv = v;
    lds[t] = xv;
    __syncthreads();
    for (int off = 1; off < 256; off <<= 1) {
        int tmp = (t >= off) ? lds[t - off] : 0;
        __syncthreads();
        xv += tmp;
        lds[t] = xv;
        __syncthreads();
    }
    if (n < N) rowptr[n + 1] = xv;
    if (t == 255) bsum[blockIdx.x] = xv;
}

__global__ void k_scan2(int* bsum, int nb) {
    __shared__ int lds[256];
    int t = threadIdx.x;
    int v = (t < nb) ? bsum[t] : 0;
    int xv = v;
    lds[t] = xv;
    __syncthreads();
    for (int off = 1; off < 256; off <<= 1) {
        int tmp = (t >= off) ? lds[t - off] : 0;
        __syncthreads();
        xv += tmp;
        lds[t] = xv;
        __syncthreads();
    }
    if (t < nb) bsum[t] = xv - v;  // exclusive
}

// finalize rowptr, init cursor (=rowptr[n]), and place self-loop at last slot
__global__ void k_scan3(int* rowptr, const int* __restrict__ bsum,
                        const int* __restrict__ deg, int* cursor, int* eidx, int N) {
    int n = blockIdx.x * 256 + threadIdx.x;
    if (n < N) {
        int val = rowptr[n + 1] + bsum[blockIdx.x];
        rowptr[n + 1] = val;
        cursor[n] = val - deg[n] - 1;  // == rowptr[n]
        eidx[val - 1] = n;             // self loop (atomic-free, deterministic slot)
    }
    if (n == 0) rowptr[0] = 0;
}

// 4 edges per thread: int4 loads, 4 atomics + 4 stores in flight
__global__ void k_scatter(const int* __restrict__ src, const int* __restrict__ dst,
                          int* cursor, int* eidx, int E) {
    int i0 = (blockIdx.x * blockDim.x + threadIdx.x) * 4;
    if (i0 + 4 <= E) {
        int4 s = *(const int4*)(src + i0);
        int4 d = *(const int4*)(dst + i0);
        int p0 = atomicAdd(&cursor[d.x], 1);
        int p1 = atomicAdd(&cursor[d.y], 1);
        int p2 = atomicAdd(&cursor[d.z], 1);
        int p3 = atomicAdd(&cursor[d.w], 1);
        eidx[p0] = s.x;
        eidx[p1] = s.y;
        eidx[p2] = s.z;
        eidx[p3] = s.w;
    } else {
        for (int i = i0; i < E; ++i) {
            int pos = atomicAdd(&cursor[dst[i]], 1);
            eidx[pos] = src[i];
        }
    }
}

// ---------------- fp32 -> bf16 cast (4 elems/thread) ----------------
__global__ void k_f2b4(const float* __restrict__ in, unsigned short* __restrict__ out, int n4) {
    int i = blockIdx.x * blockDim.x + threadIdx.x;
    if (i >= n4) return;
    float4 v = ((const float4*)in)[i];
    ushort4 o = make_ushort4(f2b(v.x), f2b(v.y), f2b(v.z), f2b(v.w));
    ((ushort4*)out)[i] = o;
}

// ---------------- weight convert+transpose: WT[c][k] = W[k][c] ----------------
__global__ void k_wcvt(const float* __restrict__ W, unsigned short* __restrict__ WT,
                       int K, int M) {
    int idx = blockIdx.x * blockDim.x + threadIdx.x;
    if (idx >= K * M) return;
    int c = idx / K, k = idx - c * K;
    WT[idx] = f2b(W[(size_t)k * M + c]);
}

// W2 special: WT2[c][j] = 0.25*W2[(j&127)*512 + (j>>7)*128 + c]  (j = h*128+k; folds head-mean)
__global__ void k_w2cvt(const float* __restrict__ W2, unsigned short* __restrict__ WT2) {
    int idx = blockIdx.x * blockDim.x + threadIdx.x;
    if (idx >= 128 * 512) return;
    int c = idx >> 9, j = idx & 511;
    WT2[idx] = f2b(0.25f * W2[(size_t)(j & 127) * 512 + (j >> 7) * 128 + c]);
}

// ---------------- LDS fragment load: two 8B reads (stride-72B rows, align 8) ----------------
__device__ __forceinline__ bf16x8 lds_frag(const unsigned short* pp) {
    union { bf16x8 v; uint2 u2[2]; } t;
    t.u2[0] = *(const uint2*)pp;
    t.u2[1] = *(const uint2*)(pp + 4);
    return t.v;
}

// ---------------- tiled MFMA GEMM: out[N,128] = A16[N,K] @ W (via WT[128][K]) ----------------
template <int K>
__global__ __launch_bounds__(256) void k_tgemm(const unsigned short* __restrict__ A,
                                               const unsigned short* __restrict__ WT,
                                               float* __restrict__ out,
                                               unsigned short* __restrict__ out16, int N) {
    __shared__ unsigned short Ast[64 * 36];   // [row][36] (72 B stride)
    __shared__ unsigned short Bst[128 * 36];  // [col][36]
    const int tid = threadIdx.x;
    const int lane = tid & 63, w = tid >> 6;
    const int l16 = lane & 15, quad = lane >> 4;
    const int rowbase = blockIdx.x * 64;
    const int sar = tid >> 2, sak = tid & 3;
    const int sbc = tid >> 1, sbk = tid & 1;
    const long arow_g = min(rowbase + sar, N - 1);

    floatx4 acc[8];
#pragma unroll
    for (int c = 0; c < 8; c++) acc[c] = (floatx4){0.f, 0.f, 0.f, 0.f};

    uint4 rA, rB0, rB1;
    const unsigned short* Ag = A + (size_t)arow_g * K + sak * 8;
    const unsigned short* Bg = WT + (size_t)sbc * K + sbk * 8;
    rA = *(const uint4*)(Ag);
    rB0 = *(const uint4*)(Bg);
    rB1 = *(const uint4*)(Bg + 16);

    unsigned short* Aw = Ast + sar * 36 + sak * 8;
    unsigned short* Bw0 = Bst + sbc * 36 + sbk * 8;
    unsigned short* Bw1 = Bw0 + 16;
    const unsigned short* Ar = Ast + (w * 16 + l16) * 36 + quad * 8;
    const unsigned short* Br = Bst + l16 * 36 + quad * 8;

#pragma unroll
    for (int k0 = 0; k0 < K; k0 += 32) {
        __syncthreads();
        *(uint2*)(Aw) = make_uint2(rA.x, rA.y);
        *(uint2*)(Aw + 4) = make_uint2(rA.z, rA.w);
        *(uint2*)(Bw0) = make_uint2(rB0.x, rB0.y);
        *(uint2*)(Bw0 + 4) = make_uint2(rB0.z, rB0.w);
        *(uint2*)(Bw1) = make_uint2(rB1.x, rB1.y);
        *(uint2*)(Bw1 + 4) = make_uint2(rB1.z, rB1.w);
        __syncthreads();
        if (k0 + 32 < K) {
            rA = *(const uint4*)(Ag + k0 + 32);
            rB0 = *(const uint4*)(Bg + k0 + 32);
            rB1 = *(const uint4*)(Bg + k0 + 48);
        }
        bf16x8 af = lds_frag(Ar);
#pragma unroll
        for (int c = 0; c < 8; c++) {
            bf16x8 bf = lds_frag(Br + c * 16 * 36);
            acc[c] = __builtin_amdgcn_mfma_f32_16x16x32_bf16(af, bf, acc[c], 0, 0, 0);
        }
    }

    const int row00 = rowbase + w * 16 + quad * 4;
#pragma unroll
    for (int c = 0; c < 8; c++) {
#pragma unroll
        for (int r = 0; r < 4; r++) {
            int row = row00 + r;
            if (row < N) {
                out[(size_t)row * 128 + c * 16 + l16] = acc[c][r];
                if (out16) out16[(size_t)row * 128 + c * 16 + l16] = f2b(acc[c][r]);
            }
        }
    }
}

// ---------------- attention scores, layers 0/1 ----------------
__global__ void k_att32(const float* __restrict__ xp, const float* __restrict__ att_s,
                        const float* __restrict__ att_d, float* __restrict__ a_s,
                        float* __restrict__ a_d, int N) {
    int wid = (blockIdx.x * blockDim.x + threadIdx.x) >> 6;
    int lane = threadIdx.x & 63;
    if (wid >= N) return;
    const float* xr = xp + (size_t)wid * 128;
    float x0 = xr[lane], x1 = xr[lane + 64];
    float ps0 = x0 * att_s[lane], ps1 = x1 * att_s[lane + 64];
    float pd0 = x0 * att_d[lane], pd1 = x1 * att_d[lane + 64];
    for (int m = 16; m >= 1; m >>= 1) {
        ps0 += __shfl_xor(ps0, m, 64);
        ps1 += __shfl_xor(ps1, m, 64);
        pd0 += __shfl_xor(pd0, m, 64);
        pd1 += __shfl_xor(pd1, m, 64);
    }
    if ((lane & 31) == 0) {
        int h = lane >> 5;
        a_s[wid * 4 + h] = ps0;
        a_s[wid * 4 + 2 + h] = ps1;
        a_d[wid * 4 + h] = pd0;
        a_d[wid * 4 + 2 + h] = pd1;
    }
}

// ---------------- layer 2 score precompute ----------------
__global__ void k_makeWt(const float* __restrict__ W2, const float* __restrict__ as2,
                         const float* __restrict__ ad2, float* __restrict__ Wt) {
    int wid = (blockIdx.x * blockDim.x + threadIdx.x) >> 6;
    int lane = threadIdx.x & 63;
    if (wid >= 1024) return;
    int k = wid & 127, hh = (wid >> 7) & 3, isd = wid >> 9;
    const float* att = isd ? ad2 : as2;
    float v = W2[(size_t)k * 512 + hh * 128 + lane] * att[hh * 128 + lane] +
              W2[(size_t)k * 512 + hh * 128 + 64 + lane] * att[hh * 128 + 64 + lane];
    for (int m = 32; m >= 1; m >>= 1) v += __shfl_xor(v, m, 64);
    if (lane == 0) Wt[isd * 512 + hh * 128 + k] = v;
}

// ---------------- layer 2 scores from h ----------------
__global__ void k_attW(const float* __restrict__ hb, const float* __restrict__ Wt,
                       float* __restrict__ a_s, float* __restrict__ a_d, int N) {
    int wid = (blockIdx.x * blockDim.x + threadIdx.x) >> 6;
    int lane = threadIdx.x & 63;
    if (wid >= N) return;
    float x0 = hb[(size_t)wid * 128 + lane], x1 = hb[(size_t)wid * 128 + 64 + lane];
    float ts[4], td[4];
#pragma unroll
    for (int hh = 0; hh < 4; hh++) {
        ts[hh] = x0 * Wt[hh * 128 + lane] + x1 * Wt[hh * 128 + 64 + lane];
        td[hh] = x0 * Wt[512 + hh * 128 + lane] + x1 * Wt[512 + hh * 128 + 64 + lane];
    }
    for (int m = 32; m >= 1; m >>= 1) {
#pragma unroll
        for (int hh = 0; hh < 4; hh++) {
            ts[hh] += __shfl_xor(ts[hh], m, 64);
            td[hh] += __shfl_xor(td[hh], m, 64);
        }
    }
    if (lane == 0) {
#pragma unroll
        for (int hh = 0; hh < 4; hh++) {
            a_s[wid * 4 + hh] = ts[hh];
            a_d[wid * 4 + hh] = td[hh];
        }
    }
}

// ---------------- edge softmax weights ----------------
__global__ void k_edgew(const float* __restrict__ a_s, const float* __restrict__ a_d,
                        const int* __restrict__ rowptr, const int* __restrict__ eidx,
                        float4* __restrict__ wp, float4* __restrict__ invden, int N) {
    int d = (blockIdx.x * blockDim.x + threadIdx.x) >> 6;
    int lane = threadIdx.x & 63;
    if (d >= N) return;
    float4 ad4 = *(const float4*)(a_d + (size_t)d * 4);
    int jb = rowptr[d], je = rowptr[d + 1], deg = je - jb;
    int j = jb + lane;
    if (deg <= 64) {
        float e[4] = {-INFINITY, -INFINITY, -INFINITY, -INFINITY};
        if (j < je) {
            int s = eidx[j];
            float4 as4 = *(const float4*)(a_s + (size_t)s * 4);
#pragma unroll
            for (int hh = 0; hh < 4; hh++)
                e[hh] = lrelu(((const float*)&as4)[hh] + ((const float*)&ad4)[hh]);
        }
        float m[4] = {e[0], e[1], e[2], e[3]};
        for (int off = 32; off >= 1; off >>= 1) {
#pragma unroll
            for (int hh = 0; hh < 4; hh++) m[hh] = fmaxf(m[hh], __shfl_xor(m[hh], off, 64));
        }
        float p[4], den[4];
#pragma unroll
        for (int hh = 0; hh < 4; hh++) {
            p[hh] = (j < je) ? __expf(e[hh] - m[hh]) : 0.f;
            den[hh] = p[hh];
        }
        for (int off = 32; off >= 1; off >>= 1) {
#pragma unroll
            for (int hh = 0; hh < 4; hh++) den[hh] += __shfl_xor(den[hh], off, 64);
        }
        if (j < je) wp[j] = make_float4(p[0], p[1], p[2], p[3]);
        if (lane == 0)
            invden[d] = make_float4(1.f / (den[0] + 1e-16f), 1.f / (den[1] + 1e-16f),
                                    1.f / (den[2] + 1e-16f), 1.f / (den[3] + 1e-16f));
    } else {
        float m[4] = {-INFINITY, -INFINITY, -INFINITY, -INFINITY};
        for (int jj = j; jj < je; jj += 64) {
            int s = eidx[jj];
            float4 as4 = *(const float4*)(a_s + (size_t)s * 4);
#pragma unroll
            for (int hh = 0; hh < 4; hh++)
                m[hh] = fmaxf(m[hh], lrelu(((const float*)&as4)[hh] + ((const float*)&ad4)[hh]));
        }
        for (int off = 32; off >= 1; off >>= 1) {
#pragma unroll
            for (int hh = 0; hh < 4; hh++) m[hh] = fmaxf(m[hh], __shfl_xor(m[hh], off, 64));
        }
        float den[4] = {0.f, 0.f, 0.f, 0.f};
        for (int jj = j; jj < je; jj += 64) {
            int s = eidx[jj];
            float4 as4 = *(const float4*)(a_s + (size_t)s * 4);
            float p[4];
#pragma unroll
            for (int hh = 0; hh < 4; hh++) {
                float e = lrelu(((const float*)&as4)[hh] + ((const float*)&ad4)[hh]);
                p[hh] = __expf(e - m[hh]);
                den[hh] += p[hh];
            }
            wp[jj] = make_float4(p[0], p[1], p[2], p[3]);
        }
        for (int off = 32; off >= 1; off >>= 1) {
#pragma unroll
            for (int hh = 0; hh < 4; hh++) den[hh] += __shfl_xor(den[hh], off, 64);
        }
        if (lane == 0)
            invden[d] = make_float4(1.f / (den[0] + 1e-16f), 1.f / (den[1] + 1e-16f),
                                    1.f / (den[2] + 1e-16f), 1.f / (den[3] + 1e-16f));
    }
}

// ---------------- accumulation, layers 0/1: bf16 gather, unroll x4 for MLP ----------------
__global__ void k_acc01(const unsigned short* __restrict__ xp16, const float* __restrict__ wp,
                        const float4* __restrict__ invden, const int* __restrict__ rowptr,
                        const int* __restrict__ eidx, const float* __restrict__ bias,
                        float* __restrict__ out, int N) {
    int d = (blockIdx.x * blockDim.x + threadIdx.x) >> 6;
    int lane = threadIdx.x & 63;
    if (d >= N) return;
    int hh = lane >> 4;
    int jb = rowptr[d], je = rowptr[d + 1];
    float a0 = 0.f, a1 = 0.f;
    int j = jb;
    for (; j + 4 <= je; j += 4) {
        int s0 = __builtin_amdgcn_readfirstlane(eidx[j]);
        int s1 = __builtin_amdgcn_readfirstlane(eidx[j + 1]);
        int s2 = __builtin_amdgcn_readfirstlane(eidx[j + 2]);
        int s3 = __builtin_amdgcn_readfirstlane(eidx[j + 3]);
        float w0 = wp[(size_t)j * 4 + hh];
        float w1 = wp[(size_t)(j + 1) * 4 + hh];
        float w2 = wp[(size_t)(j + 2) * 4 + hh];
        float w3 = wp[(size_t)(j + 3) * 4 + hh];
        unsigned int u0 = *(const unsigned int*)(xp16 + (size_t)s0 * 128 + 2 * lane);
        unsigned int u1 = *(const unsigned int*)(xp16 + (size_t)s1 * 128 + 2 * lane);
        unsigned int u2 = *(const unsigned int*)(xp16 + (size_t)s2 * 128 + 2 * lane);
        unsigned int u3 = *(const unsigned int*)(xp16 + (size_t)s3 * 128 + 2 * lane);
        a0 += w0 * b2f_lo(u0) + w1 * b2f_lo(u1) + w2 * b2f_lo(u2) + w3 * b2f_lo(u3);
        a1 += w0 * b2f_hi(u0) + w1 * b2f_hi(u1) + w2 * b2f_hi(u2) + w3 * b2f_hi(u3);
    }
    for (; j < je; ++j) {
        int s = __builtin_amdgcn_readfirstlane(eidx[j]);
        float w = wp[(size_t)j * 4 + hh];
        unsigned int u = *(const unsigned int*)(xp16 + (size_t)s * 128 + 2 * lane);
        a0 += w * b2f_lo(u);
        a1 += w * b2f_hi(u);
    }
    float inv = ((const float*)(invden + d))[hh];
    float2 o = make_float2(a0 * inv + bias[2 * lane], a1 * inv + bias[2 * lane + 1]);
    *(float2*)(out + (size_t)d * 128 + 2 * lane) = o;
}

// ---------------- accumulation, layer 2: bf16 gather shared by 4 heads, unroll x4 ----------------
__global__ void k_accL2(const unsigned short* __restrict__ hb16, const float4* __restrict__ wp,
                        const float4* __restrict__ invden, const int* __restrict__ rowptr,
                        const int* __restrict__ eidx, unsigned short* __restrict__ agg16,
                        int N) {
    int d = (blockIdx.x * blockDim.x + threadIdx.x) >> 6;
    int lane = threadIdx.x & 63;
    if (d >= N) return;
    int jb = rowptr[d], je = rowptr[d + 1];
    float acc[4][2] = {{0.f, 0.f}, {0.f, 0.f}, {0.f, 0.f}, {0.f, 0.f}};
    int j = jb;
    for (; j + 4 <= je; j += 4) {
        int s0 = __builtin_amdgcn_readfirstlane(eidx[j]);
        int s1 = __builtin_amdgcn_readfirstlane(eidx[j + 1]);
        int s2 = __builtin_amdgcn_readfirstlane(eidx[j + 2]);
        int s3 = __builtin_amdgcn_readfirstlane(eidx[j + 3]);
        float4 w0 = wp[j], w1 = wp[j + 1], w2 = wp[j + 2], w3 = wp[j + 3];
        unsigned int u0 = *(const unsigned int*)(hb16 + (size_t)s0 * 128 + 2 * lane);
        unsigned int u1 = *(const unsigned int*)(hb16 + (size_t)s1 * 128 + 2 * lane);
        unsigned int u2 = *(const unsigned int*)(hb16 + (size_t)s2 * 128 + 2 * lane);
        unsigned int u3 = *(const unsigned int*)(hb16 + (size_t)s3 * 128 + 2 * lane);
        float lo0 = b2f_lo(u0), hi0 = b2f_hi(u0);
        float lo1 = b2f_lo(u1), hi1 = b2f_hi(u1);
        float lo2 = b2f_lo(u2), hi2 = b2f_hi(u2);
        float lo3 = b2f_lo(u3), hi3 = b2f_hi(u3);
#pragma unroll
        for (int hh = 0; hh < 4; hh++) {
            acc[hh][0] += ((const float*)&w0)[hh] * lo0 + ((const float*)&w1)[hh] * lo1 +
                          ((const float*)&w2)[hh] * lo2 + ((const float*)&w3)[hh] * lo3;
            acc[hh][1] += ((const float*)&w0)[hh] * hi0 + ((const float*)&w1)[hh] * hi1 +
                          ((const float*)&w2)[hh] * hi2 + ((const float*)&w3)[hh] * hi3;
        }
    }
    for (; j < je; ++j) {
        int s = __builtin_amdgcn_readfirstlane(eidx[j]);
        float4 w = wp[j];
        unsigned int u = *(const unsigned int*)(hb16 + (size_t)s * 128 + 2 * lane);
        float lo = b2f_lo(u), hi = b2f_hi(u);
#pragma unroll
        for (int hh = 0; hh < 4; hh++) {
            acc[hh][0] += ((const float*)&w)[hh] * lo;
            acc[hh][1] += ((const float*)&w)[hh] * hi;
        }
    }
    float4 inv = invden[d];
#pragma unroll
    for (int hh = 0; hh < 4; hh++) {
        float iv = ((const float*)&inv)[hh];
        ushort2 o = make_ushort2(f2b(acc[hh][0] * iv), f2b(acc[hh][1] * iv));
        *(ushort2*)(agg16 + (size_t)d * 512 + hh * 128 + 2 * lane) = o;
    }
}

// ---------------- batch norm ----------------
__global__ void k_bnstats(const float* __restrict__ x, float* __restrict__ sums, int N) {
    int col = threadIdx.x & 127, half = threadIdx.x >> 7;
    float s1 = 0.f, s2 = 0.f;
    for (int r = blockIdx.x * 2 + half; r < N; r += gridDim.x * 2) {
        float v = x[(size_t)r * 128 + col];
        s1 += v;
        s2 += v * v;
    }
    atomicAdd(&sums[col], s1);
    atomicAdd(&sums[128 + col], s2);
}

// normalize (+ELU) in place; optionally also emit bf16 copy for the next GEMM
__global__ void k_bnapply(float* __restrict__ x, unsigned short* __restrict__ out16,
                          const float* __restrict__ sums, const float* __restrict__ gamma,
                          const float* __restrict__ beta, int N, int elu) {
    int idx = blockIdx.x * blockDim.x + threadIdx.x;  // float4 index
    if (idx >= N * 32) return;
    float4 v = ((float4*)x)[idx];
    int colb = (idx & 31) * 4;
    float invN = 1.f / (float)N;
#pragma unroll
    for (int j = 0; j < 4; j++) {
        int col = colb + j;
        float mu = sums[col] * invN;
        float var = sums[128 + col] * invN - mu * mu;
        float y = (((float*)&v)[j] - mu) * rsqrtf(var + EPS_BN) * gamma[col] + beta[col];
        if (elu) y = y > 0.f ? y : __expf(y) - 1.f;
        ((float*)&v)[j] = y;
    }
    ((float4*)x)[idx] = v;
    if (out16) {
        ushort4 o = make_ushort4(f2b(v.x), f2b(v.y), f2b(v.z), f2b(v.w));
        ((ushort4*)out16)[idx] = o;
    }
}

// ---------------- launch ----------------
extern "C" void kernel_launch(void* const* d_in, const int* in_sizes, int n_in,
                              void* d_out, int out_size, void* d_ws, size_t ws_size,
                              hipStream_t stream) {
    const float* x = (const float*)d_in[0];
    const int* ei_raw = (const int*)d_in[1];
    const float* W0 = (const float*)d_in[2];
    const float* as0 = (const float*)d_in[3];
    const float* ad0 = (const float*)d_in[4];
    const float* b0 = (const float*)d_in[5];
    const float* g0 = (const float*)d_in[6];
    const float* be0 = (const float*)d_in[7];
    const float* W1 = (const float*)d_in[8];
    const float* as1 = (const float*)d_in[9];
    const float* ad1 = (const float*)d_in[10];
    const float* b1 = (const float*)d_in[11];
    const float* g1 = (const float*)d_in[12];
    const float* be1 = (const float*)d_in[13];
    const float* W2 = (const float*)d_in[14];
    const float* as2 = (const float*)d_in[15];
    const float* ad2 = (const float*)d_in[16];
    const float* g2v = (const float*)d_in[18];
    const float* be2 = (const float*)d_in[19];

    const int N = in_sizes[0] / 128;
    const int E = in_sizes[1] / 2;

    // workspace carve (256B aligned)
    char* p = (char*)d_ws;
    auto alloc = [&](size_t bytes) {
        void* r = (void*)p;
        p += (bytes + 255) & ~(size_t)255;
        return r;
    };
    float* xp = (float*)alloc((size_t)N * 128 * 4);      // per-layer projected features (fp32)
    float* hbuf = (float*)alloc((size_t)N * 128 * 4);    // hidden (fp32)
    unsigned short* xb = (unsigned short*)alloc((size_t)N * 128 * 2);    // bf16 of x
    unsigned short* xp16 = (unsigned short*)alloc((size_t)N * 128 * 2);  // bf16 of xp (gather payload)
    unsigned short* hb16 = (unsigned short*)alloc((size_t)N * 128 * 2);  // bf16 of hbuf
    unsigned short* agg16 = (unsigned short*)alloc((size_t)N * 512 * 2); // bf16 layer-2 aggregate
    float* As = (float*)alloc((size_t)N * 4 * 4);
    float* Ad = (float*)alloc((size_t)N * 4 * 4);
    int* deg = (int*)alloc((size_t)N * 4);
    int* rowptr = (int*)alloc((size_t)(N + 1) * 4);
    int* cursor = (int*)alloc((size_t)N * 4);
    int* bsum = (int*)alloc(1024);
    int* eidx = (int*)alloc((size_t)(E + N) * 4);
    float* bns = (float*)alloc(256 * 4);
    // union: ei32 (2E ints, CSR build only) then wp ((E+N) float4)
    size_t uni_bytes = (size_t)(E + N) * 16;
    size_t ei_bytes = (size_t)2 * E * 4;
    char* uni = (char*)alloc(uni_bytes > ei_bytes ? uni_bytes : ei_bytes);
    int* ei32 = (int*)uni;
    float4* wp = (float4*)uni;
    float4* invden = (float4*)alloc((size_t)N * 16);
    int* flag = (int*)alloc(256);
    float* Wt = (float*)alloc(1024 * 4);
    unsigned short* WT0 = (unsigned short*)alloc((size_t)128 * 128 * 2);
    unsigned short* WT1 = (unsigned short*)alloc((size_t)128 * 128 * 2);
    unsigned short* WT2 = (unsigned short*)alloc((size_t)128 * 512 * 2);
    if ((size_t)(p - (char*)d_ws) > ws_size) return;

    const int nb = (N + 255) / 256;
    const int gw = (N + 3) / 4;              // wave-per-node kernels
    const int gt = (N + 63) / 64;            // tiled GEMM: 64 rows per block
    const int g4e = (E + 1023) / 1024;       // 4-edges-per-thread kernels

    // --- edge dtype normalize ---
    k_detect64<<<1, 64, 0, stream>>>(ei_raw, flag, 2 * E);
    k_convert<<<(2 * E + 1023) / 1024, 256, 0, stream>>>(ei_raw, flag, ei32, 2 * E);
    const int* srcv = ei32;
    const int* dstv = ei32 + E;

    // --- CSR build ---
    hipMemsetAsync(deg, 0, (size_t)N * 4, stream);
    k_deg_count<<<g4e, 256, 0, stream>>>(dstv, deg, E);
    k_scan1<<<nb, 256, 0, stream>>>(deg, rowptr, bsum, N);
    k_scan2<<<1, 256, 0, stream>>>(bsum, nb);
    k_scan3<<<nb, 256, 0, stream>>>(rowptr, bsum, deg, cursor, eidx, N);
    k_scatter<<<g4e, 256, 0, stream>>>(srcv, dstv, cursor, eidx, E);

    // --- weight prep (bf16 transposed) + input cast ---
    k_wcvt<<<(128 * 128 + 255) / 256, 256, 0, stream>>>(W0, WT0, 128, 128);
    k_wcvt<<<(128 * 128 + 255) / 256, 256, 0, stream>>>(W1, WT1, 128, 128);
    k_w2cvt<<<(128 * 512 + 255) / 256, 256, 0, stream>>>(W2, WT2);
    k_makeWt<<<256, 256, 0, stream>>>(W2, as2, ad2, Wt);
    k_f2b4<<<(N * 32 + 255) / 256, 256, 0, stream>>>(x, xb, N * 32);

    // --- layer 0 ---
    k_tgemm<128><<<gt, 256, 0, stream>>>(xb, WT0, xp, xp16, N);
    k_att32<<<gw, 256, 0, stream>>>(xp, as0, ad0, As, Ad, N);
    k_edgew<<<gw, 256, 0, stream>>>(As, Ad, rowptr, eidx, wp, invden, N);
    k_acc01<<<gw, 256, 0, stream>>>(xp16, (const float*)wp, invden, rowptr, eidx, b0, hbuf, N);
    hipMemsetAsync(bns, 0, 256 * 4, stream);
    k_bnstats<<<256, 256, 0, stream>>>(hbuf, bns, N);
    k_bnapply<<<(N * 32 + 255) / 256, 256, 0, stream>>>(hbuf, hb16, bns, g0, be0, N, 1);

    // --- layer 1 ---
    k_tgemm<128><<<gt, 256, 0, stream>>>(hb16, WT1, xp, xp16, N);
    k_att32<<<gw, 256, 0, stream>>>(xp, as1, ad1, As, Ad, N);
    k_edgew<<<gw, 256, 0, stream>>>(As, Ad, rowptr, eidx, wp, invden, N);
    k_acc01<<<gw, 256, 0, stream>>>(xp16, (const float*)wp, invden, rowptr, eidx, b1, hbuf, N);
    hipMemsetAsync(bns, 0, 256 * 4, stream);
    k_bnstats<<<256, 256, 0, stream>>>(hbuf, bns, N);
    k_bnapply<<<(N * 32 + 255) / 256, 256, 0, stream>>>(hbuf, hb16, bns, g1, be1, N, 1);

    // --- layer 2 (linearity: aggregate h per head, then [N,512]@[512,128] MFMA GEMM) ---
    float* outf = (float*)d_out;
    k_attW<<<gw, 256, 0, stream>>>(hbuf, Wt, As, Ad, N);
    k_edgew<<<gw, 256, 0, stream>>>(As, Ad, rowptr, eidx, wp, invden, N);
    k_accL2<<<gw, 256, 0, stream>>>(hb16, wp, invden, rowptr, eidx, agg16, N);
    k_tgemm<512><<<gt, 256, 0, stream>>>(agg16, WT2, outf, (unsigned short*)nullptr, N);
    hipMemsetAsync(bns, 0, 256 * 4, stream);
    k_bnstats<<<256, 256, 0, stream>>>(outf, bns, N);
    k_bnapply<<<(N * 32 + 255) / 256, 256, 0, stream>>>(outf, (unsigned short*)nullptr, bns, g2v, be2, N, 0);
}